// Round 1
// baseline (1116.067 us; speedup 1.0000x reference)
//
#include <hip/hip_runtime.h>
#include <hip/hip_bf16.h>
#include <math.h>

#define N_NODES 30000
#define IN_DIM  256
#define OUT_DIM 256
#define NHEAD   4
#define HDIM    64
#define NTYPES  5
#define EPT     40000
#define TE      (NTYPES * EPT)

// ---- monotone float<->uint encoding for atomicMax on f32 (handles negatives) ----
__device__ __forceinline__ unsigned fenc(float f) {
    unsigned u = __float_as_uint(f);
    return (u & 0x80000000u) ? ~u : (u | 0x80000000u);
}
__device__ __forceinline__ float fdec(unsigned e) {
    unsigned u = (e & 0x80000000u) ? (e ^ 0x80000000u) : ~e;
    return __uint_as_float(u);
}

// ---- init: zero aggV/expsum, amax = enc(-inf) ----
__global__ __launch_bounds__(256) void init_kernel(float* __restrict__ aggV,
                                                   float* __restrict__ expsum,
                                                   unsigned* __restrict__ amax) {
    const int stride = gridDim.x * blockDim.x;
    const int gid = blockIdx.x * blockDim.x + threadIdx.x;
    for (int i = gid; i < N_NODES * OUT_DIM; i += stride) aggV[i] = 0.f;
    for (int i = gid; i < N_NODES * NHEAD; i += stride) {
        expsum[i] = 0.f;
        amax[i] = 0x007FFFFFu;  // enc(-inf)
    }
}

// ---- generic f32 GEMM: C[M,N] = A[M,K] @ W[N,K]^T + bias; mode 1 fuses skip blend ----
__global__ __launch_bounds__(256) void gemm_bias(const float* __restrict__ A,
                                                 const float* __restrict__ W,
                                                 const float* __restrict__ bias,
                                                 float* __restrict__ C,
                                                 int M, int N, int K, int mode,
                                                 const float* __restrict__ hres,
                                                 const float* __restrict__ skip) {
    __shared__ float As[16][68];
    __shared__ float Bs[16][68];
    const int row0 = blockIdx.x * 64, col0 = blockIdx.y * 64;
    const int t = threadIdx.x;
    const int tx = t & 15, ty = t >> 4;
    const int lrow = t >> 2, lk4 = (t & 3) << 2;
    float acc[4][4] = {};
    for (int kt = 0; kt < K; kt += 16) {
        float4 a4 = make_float4(0.f, 0.f, 0.f, 0.f);
        float4 b4 = make_float4(0.f, 0.f, 0.f, 0.f);
        const int ar = row0 + lrow;
        if (ar < M) a4 = *(const float4*)(A + (size_t)ar * K + kt + lk4);
        const int wr = col0 + lrow;
        if (wr < N) b4 = *(const float4*)(W + (size_t)wr * K + kt + lk4);
        As[lk4 + 0][lrow] = a4.x; As[lk4 + 1][lrow] = a4.y;
        As[lk4 + 2][lrow] = a4.z; As[lk4 + 3][lrow] = a4.w;
        Bs[lk4 + 0][lrow] = b4.x; Bs[lk4 + 1][lrow] = b4.y;
        Bs[lk4 + 2][lrow] = b4.z; Bs[lk4 + 3][lrow] = b4.w;
        __syncthreads();
#pragma unroll
        for (int k = 0; k < 16; ++k) {
            const float4 av = *(const float4*)&As[k][ty << 2];
            const float4 bv = *(const float4*)&Bs[k][tx << 2];
            const float aa[4] = {av.x, av.y, av.z, av.w};
            const float bb[4] = {bv.x, bv.y, bv.z, bv.w};
#pragma unroll
            for (int i = 0; i < 4; ++i)
#pragma unroll
                for (int j = 0; j < 4; ++j)
                    acc[i][j] = fmaf(aa[i], bb[j], acc[i][j]);
        }
        __syncthreads();
    }
    float sa = 1.f, sb = 0.f;
    if (mode == 1) {
        const float s = skip[0];
        sa = 1.f / (1.f + expf(-s));
        sb = 1.f - sa;
    }
#pragma unroll
    for (int i = 0; i < 4; ++i) {
        const int r = row0 + (ty << 2) + i;
        if (r >= M) continue;
#pragma unroll
        for (int j = 0; j < 4; ++j) {
            const int c = col0 + (tx << 2) + j;
            float v = acc[i][j] + bias[c];
            if (mode == 1) v = sa * v + sb * hres[(size_t)r * N + c];
            C[(size_t)r * N + c] = v;
        }
    }
}

// ---- alpha: one wave per edge; K_rel = K[src] @ k_rel[t]; alpha = <Q[tgt], K_rel>*scale*p_rel ----
__global__ __launch_bounds__(256) void alpha_kernel(const float* __restrict__ kqv,
                                                    const int* __restrict__ esrc,
                                                    const int* __restrict__ etgt,
                                                    const float* __restrict__ k_rel,
                                                    const float* __restrict__ p_rel,
                                                    float* __restrict__ alpha,
                                                    unsigned* __restrict__ amax) {
    __shared__ float krel_s[4096];
    __shared__ float krow_s[4][288];  // 4 waves x (4 heads x stride 72)
    const int e0 = blockIdx.x << 2;
    const int ty_ = e0 / EPT;  // all 4 edges of this block share one type (EPT % 4 == 0)
    const float* kr = k_rel + (size_t)ty_ * 4096;
    for (int i = threadIdx.x; i < 1024; i += 256)
        ((float4*)krel_s)[i] = ((const float4*)kr)[i];
    const int wid = threadIdx.x >> 6, lane = threadIdx.x & 63;
    const int e = e0 + wid;
    const int src = esrc[e], tgt = etgt[e];
    const int h = lane >> 4, f0 = (lane & 15) << 2;
    const float4 kv = *(const float4*)(kqv + (size_t)src * 768 + (lane << 2));
    const float4 qv = *(const float4*)(kqv + (size_t)tgt * 768 + 256 + (lane << 2));
    __syncthreads();
    *(float4*)&krow_s[wid][h * 72 + f0] = kv;
    __syncthreads();
    float4 acc = make_float4(0.f, 0.f, 0.f, 0.f);
    const float* kb = &krow_s[wid][h * 72];
#pragma unroll 8
    for (int d = 0; d < 64; ++d) {
        const float k = kb[d];
        const float4 r = *(const float4*)&krel_s[(d << 6) + f0];
        acc.x = fmaf(k, r.x, acc.x);
        acc.y = fmaf(k, r.y, acc.y);
        acc.z = fmaf(k, r.z, acc.z);
        acc.w = fmaf(k, r.w, acc.w);
    }
    float part = acc.x * qv.x + acc.y * qv.y + acc.z * qv.z + acc.w * qv.w;
    part += __shfl_xor(part, 1);
    part += __shfl_xor(part, 2);
    part += __shfl_xor(part, 4);
    part += __shfl_xor(part, 8);
    if ((lane & 15) == 0) {
        const float al = part * 0.125f * p_rel[ty_ * NHEAD + h];
        alpha[(size_t)e * NHEAD + h] = al;
        atomicMax(&amax[tgt * NHEAD + h], fenc(al));
    }
}

// ---- exp(alpha - amax) in place + segment sum of exps ----
__global__ __launch_bounds__(256) void expsum_kernel(float* __restrict__ alpha,
                                                     const int* __restrict__ etgt,
                                                     const unsigned* __restrict__ amax,
                                                     float* __restrict__ expsum) {
    const int i = blockIdx.x * blockDim.x + threadIdx.x;
    if (i >= TE * NHEAD) return;
    const int e = i >> 2, h = i & 3;
    const int tgt = etgt[e];
    const float m = fdec(amax[tgt * NHEAD + h]);
    const float ex = expf(alpha[i] - m);
    alpha[i] = ex;
    atomicAdd(&expsum[tgt * NHEAD + h], ex);
}

// ---- message: V_rel = V[src] @ v_rel[t]; aggV[tgt] += attn * V_rel ----
__global__ __launch_bounds__(256) void message_kernel(const float* __restrict__ kqv,
                                                      const int* __restrict__ esrc,
                                                      const int* __restrict__ etgt,
                                                      const float* __restrict__ v_rel,
                                                      const float* __restrict__ alpha_exp,
                                                      const float* __restrict__ expsum,
                                                      float* __restrict__ aggV) {
    __shared__ float vrel_s[4096];
    __shared__ float vrow_s[4][288];
    const int e0 = blockIdx.x << 2;
    const int ty_ = e0 / EPT;
    const float* vr = v_rel + (size_t)ty_ * 4096;
    for (int i = threadIdx.x; i < 1024; i += 256)
        ((float4*)vrel_s)[i] = ((const float4*)vr)[i];
    const int wid = threadIdx.x >> 6, lane = threadIdx.x & 63;
    const int e = e0 + wid;
    const int src = esrc[e], tgt = etgt[e];
    const int h = lane >> 4, f0 = (lane & 15) << 2;
    const float4 vv = *(const float4*)(kqv + (size_t)src * 768 + 512 + (lane << 2));
    __syncthreads();
    *(float4*)&vrow_s[wid][h * 72 + f0] = vv;
    __syncthreads();
    float4 acc = make_float4(0.f, 0.f, 0.f, 0.f);
    const float* vb = &vrow_s[wid][h * 72];
#pragma unroll 8
    for (int d = 0; d < 64; ++d) {
        const float v = vb[d];
        const float4 r = *(const float4*)&vrel_s[(d << 6) + f0];
        acc.x = fmaf(v, r.x, acc.x);
        acc.y = fmaf(v, r.y, acc.y);
        acc.z = fmaf(v, r.z, acc.z);
        acc.w = fmaf(v, r.w, acc.w);
    }
    const float at = alpha_exp[(size_t)e * NHEAD + h] / (expsum[tgt * NHEAD + h] + 1e-16f);
    float* dst = aggV + (size_t)tgt * OUT_DIM + (h << 6) + f0;
    atomicAdd(dst + 0, at * acc.x);
    atomicAdd(dst + 1, at * acc.y);
    atomicAdd(dst + 2, at * acc.z);
    atomicAdd(dst + 3, at * acc.w);
}

// ---- exact gelu in place ----
__global__ __launch_bounds__(256) void gelu_kernel(float* __restrict__ x) {
    const int stride = gridDim.x * blockDim.x;
    for (int i = blockIdx.x * blockDim.x + threadIdx.x; i < N_NODES * OUT_DIM; i += stride) {
        const float v = x[i];
        x[i] = 0.5f * v * (1.f + erff(v * 0.7071067811865475f));
    }
}

extern "C" void kernel_launch(void* const* d_in, const int* in_sizes, int n_in,
                              void* d_out, int out_size, void* d_ws, size_t ws_size,
                              hipStream_t stream) {
    const float* h      = (const float*)d_in[0];
    const int*   esrc   = (const int*)d_in[1];
    const int*   etgt   = (const int*)d_in[2];
    const float* kqv_w  = (const float*)d_in[3];
    const float* kqv_b  = (const float*)d_in[4];
    const float* out_w  = (const float*)d_in[5];
    const float* out_b  = (const float*)d_in[6];
    const float* k_rel  = (const float*)d_in[7];
    const float* v_rel  = (const float*)d_in[8];
    const float* skip   = (const float*)d_in[9];
    const float* p_rel  = (const float*)d_in[10];
    float* out = (float*)d_out;

    // workspace layout (floats):
    float* ws = (float*)d_ws;
    float*    kqv    = ws;                       // 30000*768   = 23,040,000
    float*    alpha  = ws + 23040000;            // 200000*4    =    800,000
    unsigned* amax   = (unsigned*)(ws + 23840000); // 30000*4   =    120,000
    float*    expsum = ws + 23960000;            // 30000*4     =    120,000
    float*    aggV   = ws + 24080000;            // 30000*256   =  7,680,000
    // total 31,760,000 floats = 127.04 MB

    hipLaunchKernelGGL(init_kernel, dim3(2048), dim3(256), 0, stream, aggV, expsum, amax);
    hipLaunchKernelGGL(gemm_bias, dim3(469, 12), dim3(256), 0, stream,
                       h, kqv_w, kqv_b, kqv, N_NODES, 768, 256, 0, nullptr, nullptr);
    hipLaunchKernelGGL(alpha_kernel, dim3(TE / 4), dim3(256), 0, stream,
                       kqv, esrc, etgt, k_rel, p_rel, alpha, amax);
    hipLaunchKernelGGL(expsum_kernel, dim3((TE * NHEAD + 255) / 256), dim3(256), 0, stream,
                       alpha, etgt, amax, expsum);
    hipLaunchKernelGGL(message_kernel, dim3(TE / 4), dim3(256), 0, stream,
                       kqv, esrc, etgt, v_rel, alpha, expsum, aggV);
    hipLaunchKernelGGL(gelu_kernel, dim3(2048), dim3(256), 0, stream, aggV);
    hipLaunchKernelGGL(gemm_bias, dim3(469, 4), dim3(256), 0, stream,
                       aggV, out_w, out_b, out, N_NODES, OUT_DIM, 256, 1, h, skip);
}

// Round 2
// 611.296 us; speedup vs baseline: 1.8257x; 1.8257x over previous
//
#include <hip/hip_runtime.h>
#include <hip/hip_bf16.h>
#include <math.h>

#define N_NODES 30000
#define IN_DIM  256
#define OUT_DIM 256
#define NHEAD   4
#define HDIM    64
#define NTYPES  5
#define EPT     40000
#define TE      (NTYPES * EPT)

// ---- monotone float<->uint encoding for atomicMax on f32 (handles negatives) ----
__device__ __forceinline__ unsigned fenc(float f) {
    unsigned u = __float_as_uint(f);
    return (u & 0x80000000u) ? ~u : (u | 0x80000000u);
}
__device__ __forceinline__ float fdec(unsigned e) {
    unsigned u = (e & 0x80000000u) ? (e ^ 0x80000000u) : ~e;
    return __uint_as_float(u);
}

__device__ __forceinline__ unsigned short f2bf(float f) {
    __hip_bfloat16 h = __float2bfloat16(f);
    return *reinterpret_cast<unsigned short*>(&h);
}

// ---- init: zero expsum/deg, amax = enc(-inf) ----
__global__ __launch_bounds__(256) void init_kernel(float* __restrict__ expsum,
                                                   unsigned* __restrict__ amax,
                                                   int* __restrict__ deg) {
    const int stride = gridDim.x * blockDim.x;
    const int gid = blockIdx.x * blockDim.x + threadIdx.x;
    for (int i = gid; i < N_NODES * NHEAD; i += stride) {
        expsum[i] = 0.f;
        amax[i] = 0x007FFFFFu;  // enc(-inf)
    }
    for (int i = gid; i < N_NODES; i += stride) deg[i] = 0;
}

// ---- CSR build: histogram ----
__global__ __launch_bounds__(256) void hist_kernel(const int* __restrict__ etgt,
                                                   int* __restrict__ deg) {
    const int stride = gridDim.x * blockDim.x;
    for (int i = blockIdx.x * blockDim.x + threadIdx.x; i < TE; i += stride)
        atomicAdd(&deg[etgt[i]], 1);
}

// ---- CSR build: single-block exclusive scan over 30000 degrees ----
__global__ __launch_bounds__(1024) void scan_kernel(const int* __restrict__ deg,
                                                    int* __restrict__ off,
                                                    int* __restrict__ cursor) {
    __shared__ int sums[1024];
    const int t = threadIdx.x;
    int local[30];
    int s = 0;
    const int base = t * 30;
#pragma unroll
    for (int j = 0; j < 30; ++j) {
        const int idx = base + j;
        const int d = (idx < N_NODES) ? deg[idx] : 0;
        local[j] = d;
        s += d;
    }
    sums[t] = s;
    __syncthreads();
    for (int d = 1; d < 1024; d <<= 1) {
        const int v = (t >= d) ? sums[t - d] : 0;
        __syncthreads();
        sums[t] += v;
        __syncthreads();
    }
    int run = (t > 0) ? sums[t - 1] : 0;
#pragma unroll
    for (int j = 0; j < 30; ++j) {
        const int idx = base + j;
        if (idx < N_NODES) {
            off[idx] = run;
            cursor[idx] = run;
            run += local[j];
        }
    }
}

// ---- CSR build: scatter edge ids into per-target buckets ----
__global__ __launch_bounds__(256) void scatter_kernel(const int* __restrict__ etgt,
                                                      int* __restrict__ cursor,
                                                      int* __restrict__ perm) {
    const int stride = gridDim.x * blockDim.x;
    for (int e = blockIdx.x * blockDim.x + threadIdx.x; e < TE; e += stride) {
        const int pos = atomicAdd(&cursor[etgt[e]], 1);
        perm[pos] = e;
    }
}

// ---- generic f32 GEMM: C[M,N] = A[M,K] @ W[N,K]^T + bias; mode 1 fuses skip blend ----
__global__ __launch_bounds__(256) void gemm_bias(const float* __restrict__ A,
                                                 const float* __restrict__ W,
                                                 const float* __restrict__ bias,
                                                 float* __restrict__ C,
                                                 int M, int N, int K, int mode,
                                                 const float* __restrict__ hres,
                                                 const float* __restrict__ skip) {
    __shared__ float As[16][68];
    __shared__ float Bs[16][68];
    const int row0 = blockIdx.x * 64, col0 = blockIdx.y * 64;
    const int t = threadIdx.x;
    const int tx = t & 15, ty = t >> 4;
    const int lrow = t >> 2, lk4 = (t & 3) << 2;
    float acc[4][4] = {};
    for (int kt = 0; kt < K; kt += 16) {
        float4 a4 = make_float4(0.f, 0.f, 0.f, 0.f);
        float4 b4 = make_float4(0.f, 0.f, 0.f, 0.f);
        const int ar = row0 + lrow;
        if (ar < M) a4 = *(const float4*)(A + (size_t)ar * K + kt + lk4);
        const int wr = col0 + lrow;
        if (wr < N) b4 = *(const float4*)(W + (size_t)wr * K + kt + lk4);
        As[lk4 + 0][lrow] = a4.x; As[lk4 + 1][lrow] = a4.y;
        As[lk4 + 2][lrow] = a4.z; As[lk4 + 3][lrow] = a4.w;
        Bs[lk4 + 0][lrow] = b4.x; Bs[lk4 + 1][lrow] = b4.y;
        Bs[lk4 + 2][lrow] = b4.z; Bs[lk4 + 3][lrow] = b4.w;
        __syncthreads();
#pragma unroll
        for (int k = 0; k < 16; ++k) {
            const float4 av = *(const float4*)&As[k][ty << 2];
            const float4 bv = *(const float4*)&Bs[k][tx << 2];
            const float aa[4] = {av.x, av.y, av.z, av.w};
            const float bb[4] = {bv.x, bv.y, bv.z, bv.w};
#pragma unroll
            for (int i = 0; i < 4; ++i)
#pragma unroll
                for (int j = 0; j < 4; ++j)
                    acc[i][j] = fmaf(aa[i], bb[j], acc[i][j]);
        }
        __syncthreads();
    }
    float sa = 1.f, sb = 0.f;
    if (mode == 1) {
        const float s = skip[0];
        sa = 1.f / (1.f + expf(-s));
        sb = 1.f - sa;
    }
#pragma unroll
    for (int i = 0; i < 4; ++i) {
        const int r = row0 + (ty << 2) + i;
        if (r >= M) continue;
#pragma unroll
        for (int j = 0; j < 4; ++j) {
            const int c = col0 + (tx << 2) + j;
            float v = acc[i][j] + bias[c];
            if (mode == 1) v = sa * v + sb * hres[(size_t)r * N + c];
            C[(size_t)r * N + c] = v;
        }
    }
}

// ---- alpha: one wave per edge; K_rel = K[src] @ k_rel[t]; alpha = <Q[tgt], K_rel>*scale*p_rel ----
__global__ __launch_bounds__(256) void alpha_kernel(const float* __restrict__ kqv,
                                                    const int* __restrict__ esrc,
                                                    const int* __restrict__ etgt,
                                                    const float* __restrict__ k_rel,
                                                    const float* __restrict__ p_rel,
                                                    float* __restrict__ alpha,
                                                    unsigned* __restrict__ amax) {
    __shared__ float krel_s[4096];
    __shared__ float krow_s[4][288];  // 4 waves x (4 heads x stride 72)
    const int e0 = blockIdx.x << 2;
    const int ty_ = e0 / EPT;  // all 4 edges of this block share one type (EPT % 4 == 0)
    const float* kr = k_rel + (size_t)ty_ * 4096;
    for (int i = threadIdx.x; i < 1024; i += 256)
        ((float4*)krel_s)[i] = ((const float4*)kr)[i];
    const int wid = threadIdx.x >> 6, lane = threadIdx.x & 63;
    const int e = e0 + wid;
    const int src = esrc[e], tgt = etgt[e];
    const int h = lane >> 4, f0 = (lane & 15) << 2;
    const float4 kv = *(const float4*)(kqv + (size_t)src * 768 + (lane << 2));
    const float4 qv = *(const float4*)(kqv + (size_t)tgt * 768 + 256 + (lane << 2));
    __syncthreads();
    *(float4*)&krow_s[wid][h * 72 + f0] = kv;
    __syncthreads();
    float4 acc = make_float4(0.f, 0.f, 0.f, 0.f);
    const float* kb = &krow_s[wid][h * 72];
#pragma unroll 8
    for (int d = 0; d < 64; ++d) {
        const float k = kb[d];
        const float4 r = *(const float4*)&krel_s[(d << 6) + f0];
        acc.x = fmaf(k, r.x, acc.x);
        acc.y = fmaf(k, r.y, acc.y);
        acc.z = fmaf(k, r.z, acc.z);
        acc.w = fmaf(k, r.w, acc.w);
    }
    float part = acc.x * qv.x + acc.y * qv.y + acc.z * qv.z + acc.w * qv.w;
    part += __shfl_xor(part, 1);
    part += __shfl_xor(part, 2);
    part += __shfl_xor(part, 4);
    part += __shfl_xor(part, 8);
    if ((lane & 15) == 0) {
        const float al = part * 0.125f * p_rel[ty_ * NHEAD + h];
        alpha[(size_t)e * NHEAD + h] = al;
        atomicMax(&amax[tgt * NHEAD + h], fenc(al));
    }
}

// ---- exp(alpha - amax) in place + segment sum of exps ----
__global__ __launch_bounds__(256) void expsum_kernel(float* __restrict__ alpha,
                                                     const int* __restrict__ etgt,
                                                     const unsigned* __restrict__ amax,
                                                     float* __restrict__ expsum) {
    const int i = blockIdx.x * blockDim.x + threadIdx.x;
    if (i >= TE * NHEAD) return;
    const int e = i >> 2, h = i & 3;
    const int tgt = etgt[e];
    const float m = fdec(amax[tgt * NHEAD + h]);
    const float ex = expf(alpha[i] - m);
    alpha[i] = ex;
    atomicAdd(&expsum[tgt * NHEAD + h], ex);
}

// ---- accumulate: one wave per target; Acat[tgt*4+h][t*64+d] = sum_e attn * V[src][h][d] (bf16) ----
__global__ __launch_bounds__(256) void accumulate_kernel(const float* __restrict__ kqv,
                                                         const int* __restrict__ esrc,
                                                         const int* __restrict__ off,
                                                         const int* __restrict__ perm,
                                                         const float* __restrict__ alpha_exp,
                                                         const float* __restrict__ expsum,
                                                         unsigned short* __restrict__ Acat) {
    const int wid = threadIdx.x >> 6, lane = threadIdx.x & 63;
    const int tgt = (blockIdx.x << 2) + wid;
    const int h = lane >> 4, f0 = (lane & 15) << 2;
    const int off0 = off[tgt];
    const int off1 = (tgt == N_NODES - 1) ? TE : off[tgt + 1];
    const int deg = off1 - off0;
    const float inv_es = 1.f / (expsum[tgt * NHEAD + h] + 1e-16f);
    float4 a0 = make_float4(0, 0, 0, 0), a1 = a0, a2 = a0, a3 = a0, a4 = a0;
    for (int i = 0; i < deg; ++i) {
        const int e = perm[off0 + i];
        const int t = e / EPT;  // uniform across wave
        const int src = esrc[e];
        const float at = alpha_exp[(size_t)e * NHEAD + h] * inv_es;
        const float4 v = *(const float4*)(kqv + (size_t)src * 768 + 512 + (h << 6) + f0);
        const float mx = at * v.x, my = at * v.y, mz = at * v.z, mw = at * v.w;
        if (t == 0)      { a0.x += mx; a0.y += my; a0.z += mz; a0.w += mw; }
        else if (t == 1) { a1.x += mx; a1.y += my; a1.z += mz; a1.w += mw; }
        else if (t == 2) { a2.x += mx; a2.y += my; a2.z += mz; a2.w += mw; }
        else if (t == 3) { a3.x += mx; a3.y += my; a3.z += mz; a3.w += mw; }
        else             { a4.x += mx; a4.y += my; a4.z += mz; a4.w += mw; }
    }
    const size_t r = (size_t)tgt * NHEAD + h;
    unsigned short* base = Acat + r * (NTYPES * HDIM) + f0;
    ushort4 u;
    u.x = f2bf(a0.x); u.y = f2bf(a0.y); u.z = f2bf(a0.z); u.w = f2bf(a0.w);
    *(ushort4*)(base + 0 * HDIM) = u;
    u.x = f2bf(a1.x); u.y = f2bf(a1.y); u.z = f2bf(a1.z); u.w = f2bf(a1.w);
    *(ushort4*)(base + 1 * HDIM) = u;
    u.x = f2bf(a2.x); u.y = f2bf(a2.y); u.z = f2bf(a2.z); u.w = f2bf(a2.w);
    *(ushort4*)(base + 2 * HDIM) = u;
    u.x = f2bf(a3.x); u.y = f2bf(a3.y); u.z = f2bf(a3.z); u.w = f2bf(a3.w);
    *(ushort4*)(base + 3 * HDIM) = u;
    u.x = f2bf(a4.x); u.y = f2bf(a4.y); u.z = f2bf(a4.z); u.w = f2bf(a4.w);
    *(ushort4*)(base + 4 * HDIM) = u;
}

// ---- epilogue GEMM: aggV[120000,64] = gelu(Acat[120000,320](bf16) @ v_rel[320,64]) ----
__global__ __launch_bounds__(256) void gemm_cat(const unsigned short* __restrict__ A,
                                                const float* __restrict__ B,
                                                float* __restrict__ C) {
    __shared__ float As[16][68];
    __shared__ float Bs[16][68];
    const int row0 = blockIdx.x * 64;
    const int t = threadIdx.x;
    const int tx = t & 15, ty = t >> 4;
    const int lrow = t >> 2, lk4 = (t & 3) << 2;
    const int br = t >> 4, bc0 = (t & 15) << 2;
    float acc[4][4] = {};
    for (int kt = 0; kt < 320; kt += 16) {
        const ushort4 a4u = *(const ushort4*)(A + (size_t)(row0 + lrow) * 320 + kt + lk4);
        const float4 b4 = *(const float4*)(B + (size_t)(kt + br) * 64 + bc0);
        As[lk4 + 0][lrow] = __uint_as_float((unsigned)a4u.x << 16);
        As[lk4 + 1][lrow] = __uint_as_float((unsigned)a4u.y << 16);
        As[lk4 + 2][lrow] = __uint_as_float((unsigned)a4u.z << 16);
        As[lk4 + 3][lrow] = __uint_as_float((unsigned)a4u.w << 16);
        Bs[br][bc0 + 0] = b4.x; Bs[br][bc0 + 1] = b4.y;
        Bs[br][bc0 + 2] = b4.z; Bs[br][bc0 + 3] = b4.w;
        __syncthreads();
#pragma unroll
        for (int k = 0; k < 16; ++k) {
            const float4 av = *(const float4*)&As[k][ty << 2];
            const float4 bv = *(const float4*)&Bs[k][tx << 2];
            const float aa[4] = {av.x, av.y, av.z, av.w};
            const float bb[4] = {bv.x, bv.y, bv.z, bv.w};
#pragma unroll
            for (int i = 0; i < 4; ++i)
#pragma unroll
                for (int j = 0; j < 4; ++j)
                    acc[i][j] = fmaf(aa[i], bb[j], acc[i][j]);
        }
        __syncthreads();
    }
#pragma unroll
    for (int i = 0; i < 4; ++i) {
        const int r = row0 + (ty << 2) + i;
#pragma unroll
        for (int j = 0; j < 4; ++j) {
            const int c = (tx << 2) + j;
            const float v = acc[i][j];
            C[(size_t)r * 64 + c] = 0.5f * v * (1.f + erff(v * 0.7071067811865475f));
        }
    }
}

extern "C" void kernel_launch(void* const* d_in, const int* in_sizes, int n_in,
                              void* d_out, int out_size, void* d_ws, size_t ws_size,
                              hipStream_t stream) {
    const float* h      = (const float*)d_in[0];
    const int*   esrc   = (const int*)d_in[1];
    const int*   etgt   = (const int*)d_in[2];
    const float* kqv_w  = (const float*)d_in[3];
    const float* kqv_b  = (const float*)d_in[4];
    const float* out_w  = (const float*)d_in[5];
    const float* out_b  = (const float*)d_in[6];
    const float* k_rel  = (const float*)d_in[7];
    const float* v_rel  = (const float*)d_in[8];
    const float* skip   = (const float*)d_in[9];
    const float* p_rel  = (const float*)d_in[10];
    float* out = (float*)d_out;

    // workspace layout (float-sized slots):
    float* ws = (float*)d_ws;
    float*    kqv    = ws;                           // 23,040,000
    float*    alpha  = ws + 23040000;                //    800,000
    unsigned* amax   = (unsigned*)(ws + 23840000);   //    120,000
    float*    expsum = ws + 23960000;                //    120,000
    float*    aggV   = ws + 24080000;                //  7,680,000
    int*      deg    = (int*)(ws + 31760000);        //     30,000
    int*      off    = (int*)(ws + 31790000);        //     30,000
    int*      cursor = (int*)(ws + 31820000);        //     30,000
    int*      perm   = (int*)(ws + 31850000);        //    200,000
    unsigned short* Acat = (unsigned short*)(ws + 32050000);  // 120000*320 bf16 = 19,200,000 slots
    // total 51,250,000 float slots = 205.0 MB

    hipLaunchKernelGGL(init_kernel, dim3(512), dim3(256), 0, stream, expsum, amax, deg);
    hipLaunchKernelGGL(hist_kernel, dim3(782), dim3(256), 0, stream, etgt, deg);
    hipLaunchKernelGGL(scan_kernel, dim3(1), dim3(1024), 0, stream, deg, off, cursor);
    hipLaunchKernelGGL(scatter_kernel, dim3(782), dim3(256), 0, stream, etgt, cursor, perm);
    hipLaunchKernelGGL(gemm_bias, dim3(469, 12), dim3(256), 0, stream,
                       h, kqv_w, kqv_b, kqv, N_NODES, 768, 256, 0, nullptr, nullptr);
    hipLaunchKernelGGL(alpha_kernel, dim3(TE / 4), dim3(256), 0, stream,
                       kqv, esrc, etgt, k_rel, p_rel, alpha, amax);
    hipLaunchKernelGGL(expsum_kernel, dim3((TE * NHEAD + 255) / 256), dim3(256), 0, stream,
                       alpha, etgt, amax, expsum);
    hipLaunchKernelGGL(accumulate_kernel, dim3(N_NODES / 4), dim3(256), 0, stream,
                       kqv, esrc, off, perm, alpha, expsum, Acat);
    hipLaunchKernelGGL(gemm_cat, dim3(120000 / 64), dim3(256), 0, stream,
                       Acat, v_rel, aggV);
    hipLaunchKernelGGL(gemm_bias, dim3(469, 4), dim3(256), 0, stream,
                       aggV, out_w, out_b, out, N_NODES, OUT_DIM, 256, 1, h, skip);
}

// Round 3
// 385.057 us; speedup vs baseline: 2.8984x; 1.5875x over previous
//
#include <hip/hip_runtime.h>
#include <hip/hip_bf16.h>
#include <math.h>

#define N_NODES 30000
#define NHEAD   4
#define HDIM    64
#define NTYPES  5
#define EPT     40000
#define TE      (NTYPES * EPT)
#define KDIM    256
#define NCAT    1792   // 1280 Ktil | 256 Q | 256 V

typedef __attribute__((ext_vector_type(8))) short short8;
typedef __attribute__((ext_vector_type(4))) float f32x4;

__device__ __forceinline__ unsigned short f2bf(float f) {
    __hip_bfloat16 h = __float2bfloat16(f);
    return *reinterpret_cast<unsigned short*>(&h);
}
__device__ __forceinline__ float bf2f(unsigned short u) {
    return __uint_as_float((unsigned)u << 16);
}

// ---- init: zero expsum and deg ----
__global__ __launch_bounds__(256) void init_kernel(float* __restrict__ expsum,
                                                   int* __restrict__ deg) {
    const int stride = gridDim.x * blockDim.x;
    const int gid = blockIdx.x * blockDim.x + threadIdx.x;
    for (int i = gid; i < N_NODES * NHEAD; i += stride) expsum[i] = 0.f;
    for (int i = gid; i < N_NODES; i += stride) deg[i] = 0;
}

// ---- CSR build: histogram ----
__global__ __launch_bounds__(256) void hist_kernel(const int* __restrict__ etgt,
                                                   int* __restrict__ deg) {
    const int stride = gridDim.x * blockDim.x;
    for (int i = blockIdx.x * blockDim.x + threadIdx.x; i < TE; i += stride)
        atomicAdd(&deg[etgt[i]], 1);
}

// ---- CSR build: single-block exclusive scan over 30000 degrees ----
__global__ __launch_bounds__(1024) void scan_kernel(const int* __restrict__ deg,
                                                    int* __restrict__ off,
                                                    int* __restrict__ cursor) {
    __shared__ int sums[1024];
    const int t = threadIdx.x;
    int local[30];
    int s = 0;
    const int base = t * 30;
#pragma unroll
    for (int j = 0; j < 30; ++j) {
        const int idx = base + j;
        const int d = (idx < N_NODES) ? deg[idx] : 0;
        local[j] = d;
        s += d;
    }
    sums[t] = s;
    __syncthreads();
    for (int d = 1; d < 1024; d <<= 1) {
        const int v = (t >= d) ? sums[t - d] : 0;
        __syncthreads();
        sums[t] += v;
        __syncthreads();
    }
    int run = (t > 0) ? sums[t - 1] : 0;
#pragma unroll
    for (int j = 0; j < 30; ++j) {
        const int idx = base + j;
        if (idx < N_NODES) {
            off[idx] = run;
            cursor[idx] = run;
            run += local[j];
        }
    }
}

// ---- CSR build: scatter edge ids into per-target buckets ----
__global__ __launch_bounds__(256) void scatter_kernel(const int* __restrict__ etgt,
                                                      int* __restrict__ cursor,
                                                      int* __restrict__ perm) {
    const int stride = gridDim.x * blockDim.x;
    for (int e = blockIdx.x * blockDim.x + threadIdx.x; e < TE; e += stride) {
        const int pos = atomicAdd(&cursor[etgt[e]], 1);
        perm[pos] = e;
    }
}

// ---- weight prep: Wcat[1792,256] bf16 (+bias_cat f32) ----
// rows [0,1280):   (t,h,d): Wtil = (W_K[h] @ k_rel[t])^T row, scaled by 0.125*p_rel[t,h]
// rows [1280,1792): Q then V rows of kqv_weight, passthrough
__global__ __launch_bounds__(256) void weight_prep(const float* __restrict__ kqv_w,
                                                   const float* __restrict__ kqv_b,
                                                   const float* __restrict__ k_rel,
                                                   const float* __restrict__ p_rel,
                                                   unsigned short* __restrict__ Wcat,
                                                   float* __restrict__ bias_cat) {
    const int r = blockIdx.x;
    const int f = threadIdx.x;
    if (r < 1280) {
        const int t = r >> 8, h = (r >> 6) & 3, d = r & 63;
        const float sc = 0.125f * p_rel[t * NHEAD + h];
        float acc = 0.f;
#pragma unroll
        for (int fp = 0; fp < 64; ++fp)
            acc = fmaf(kqv_w[(size_t)(h * 64 + fp) * 256 + f], k_rel[t * 4096 + fp * 64 + d], acc);
        Wcat[(size_t)r * 256 + f] = f2bf(acc * sc);
        if (f == 0) {
            float b = 0.f;
#pragma unroll
            for (int fp = 0; fp < 64; ++fp)
                b = fmaf(kqv_b[h * 64 + fp], k_rel[t * 4096 + fp * 64 + d], b);
            bias_cat[r] = b * sc;
        }
    } else {
        const int src_row = r - 1024;  // 1280->256 (Q), 1536->512 (V), contiguous
        Wcat[(size_t)r * 256 + f] = f2bf(kqv_w[(size_t)src_row * 256 + f]);
        if (f == 0) bias_cat[r] = kqv_b[src_row];
    }
}

// ---- h -> bf16 ----
__global__ __launch_bounds__(256) void h2bf_kernel(const float* __restrict__ h,
                                                   unsigned short* __restrict__ hb) {
    const int i = blockIdx.x * 256 + threadIdx.x;
    if (i >= N_NODES * KDIM / 4) return;
    const float4 v = ((const float4*)h)[i];
    ushort4 u;
    u.x = f2bf(v.x); u.y = f2bf(v.y); u.z = f2bf(v.z); u.w = f2bf(v.w);
    ((ushort4*)hb)[i] = u;
}

// ---- MFMA GEMM: Ccat[30000,1792](bf16) = hb[30000,256] @ Wcat^T + bias_cat ----
// 128x128 tile, BK=32, 4 waves (2x2), each wave 64x64 via 4x4 frags of 16x16x32.
// LDS rows padded to 40 bf16 (80B): 16B-aligned, 2-way max bank aliasing (free).
__global__ __launch_bounds__(256) void mfma_gemm(const unsigned short* __restrict__ hb,
                                                 const unsigned short* __restrict__ Wcat,
                                                 const float* __restrict__ bias_cat,
                                                 unsigned short* __restrict__ Ccat) {
    __shared__ unsigned short As[128 * 40];
    __shared__ unsigned short Bs[128 * 40];
    const int brow0 = blockIdx.x * 128;
    const int bcol0 = blockIdx.y * 128;
    const int t = threadIdx.x;
    const int wid = t >> 6, lane = t & 63;
    const int wr = wid >> 1, wc = wid & 1;
    const int lrow = lane & 15, kb = lane >> 4;
    // staging: 512 chunks of 16B per operand; thread handles chunks t and t+256
    const int r0 = t >> 2, q0 = t & 3;
    const int r1 = (t + 256) >> 2, q1 = t & 3;

    f32x4 acc[4][4];
#pragma unroll
    for (int m = 0; m < 4; ++m)
#pragma unroll
        for (int n = 0; n < 4; ++n) acc[m][n] = (f32x4)0.f;

    for (int kt = 0; kt < KDIM; kt += 32) {
        const int ar0 = min(brow0 + r0, N_NODES - 1);
        const int ar1 = min(brow0 + r1, N_NODES - 1);
        const uint4 a0 = *(const uint4*)(hb + (size_t)ar0 * KDIM + kt + q0 * 8);
        const uint4 a1 = *(const uint4*)(hb + (size_t)ar1 * KDIM + kt + q1 * 8);
        const uint4 b0 = *(const uint4*)(Wcat + (size_t)(bcol0 + r0) * KDIM + kt + q0 * 8);
        const uint4 b1 = *(const uint4*)(Wcat + (size_t)(bcol0 + r1) * KDIM + kt + q1 * 8);
        __syncthreads();  // previous iteration's frag reads complete before overwrite
        *(uint4*)&As[r0 * 40 + q0 * 8] = a0;
        *(uint4*)&As[r1 * 40 + q1 * 8] = a1;
        *(uint4*)&Bs[r0 * 40 + q0 * 8] = b0;
        *(uint4*)&Bs[r1 * 40 + q1 * 8] = b1;
        __syncthreads();
        short8 af[4], bf_[4];
#pragma unroll
        for (int m = 0; m < 4; ++m)
            af[m] = *(const short8*)&As[(wr * 64 + m * 16 + lrow) * 40 + kb * 8];
#pragma unroll
        for (int n = 0; n < 4; ++n)
            bf_[n] = *(const short8*)&Bs[(wc * 64 + n * 16 + lrow) * 40 + kb * 8];
#pragma unroll
        for (int m = 0; m < 4; ++m)
#pragma unroll
            for (int n = 0; n < 4; ++n)
                acc[m][n] = __builtin_amdgcn_mfma_f32_16x16x32_bf16(af[m], bf_[n], acc[m][n], 0, 0, 0);
    }

    float bias4[4];
#pragma unroll
    for (int n = 0; n < 4; ++n) bias4[n] = bias_cat[bcol0 + wc * 64 + n * 16 + lrow];
#pragma unroll
    for (int m = 0; m < 4; ++m) {
        const int gr0 = brow0 + wr * 64 + m * 16 + kb * 4;
#pragma unroll
        for (int v = 0; v < 4; ++v) {
            const int grow = gr0 + v;
            if (grow < N_NODES) {
#pragma unroll
                for (int n = 0; n < 4; ++n) {
                    const int gcol = bcol0 + wc * 64 + n * 16 + lrow;
                    Ccat[(size_t)grow * NCAT + gcol] = f2bf(acc[m][n][v] + bias4[n]);
                }
            }
        }
    }
}

// ---- alpha: one wave per edge; alpha = <Q[tgt,h], Ktil[src,t,h]> (scale pre-folded);
//      exp (no max-sub needed, |alpha| small) + expsum atomic fused ----
__global__ __launch_bounds__(256) void alpha_kernel(const unsigned short* __restrict__ Ccat,
                                                    const int* __restrict__ esrc,
                                                    const int* __restrict__ etgt,
                                                    float* __restrict__ alpha_exp,
                                                    float* __restrict__ expsum) {
    const int wid = threadIdx.x >> 6, lane = threadIdx.x & 63;
    const int e = (blockIdx.x << 2) + wid;
    const int t = e / EPT;
    const int src = esrc[e], tgt = etgt[e];
    const int h = lane >> 4, f0 = (lane & 15) << 2;
    const ushort4 qu = *(const ushort4*)(Ccat + (size_t)tgt * NCAT + 1280 + h * 64 + f0);
    const ushort4 ku = *(const ushort4*)(Ccat + (size_t)src * NCAT + (t * 4 + h) * 64 + f0);
    float part = bf2f(qu.x) * bf2f(ku.x) + bf2f(qu.y) * bf2f(ku.y)
               + bf2f(qu.z) * bf2f(ku.z) + bf2f(qu.w) * bf2f(ku.w);
    part += __shfl_xor(part, 1);
    part += __shfl_xor(part, 2);
    part += __shfl_xor(part, 4);
    part += __shfl_xor(part, 8);
    if ((lane & 15) == 0) {
        const float ex = expf(part);
        alpha_exp[(size_t)e * NHEAD + h] = ex;
        atomicAdd(&expsum[tgt * NHEAD + h], ex);
    }
}

// ---- accumulate: one wave per target; Acat[tgt*4+h][t*64+d] = sum_e attn * V[src][h][d] (bf16) ----
__global__ __launch_bounds__(256) void accumulate_kernel(const unsigned short* __restrict__ Ccat,
                                                         const int* __restrict__ esrc,
                                                         const int* __restrict__ off,
                                                         const int* __restrict__ perm,
                                                         const float* __restrict__ alpha_exp,
                                                         const float* __restrict__ expsum,
                                                         unsigned short* __restrict__ Acat) {
    const int wid = threadIdx.x >> 6, lane = threadIdx.x & 63;
    const int tgt = (blockIdx.x << 2) + wid;
    const int h = lane >> 4, f0 = (lane & 15) << 2;
    const int off0 = off[tgt];
    const int off1 = (tgt == N_NODES - 1) ? TE : off[tgt + 1];
    const int deg = off1 - off0;
    const float inv_es = 1.f / (expsum[tgt * NHEAD + h] + 1e-16f);
    float4 a0 = make_float4(0, 0, 0, 0), a1 = a0, a2 = a0, a3 = a0, a4 = a0;
    for (int i = 0; i < deg; ++i) {
        const int e = perm[off0 + i];
        const int t = e / EPT;  // uniform across wave
        const int src = esrc[e];
        const float at = alpha_exp[(size_t)e * NHEAD + h] * inv_es;
        const ushort4 vu = *(const ushort4*)(Ccat + (size_t)src * NCAT + 1536 + (h << 6) + f0);
        const float mx = at * bf2f(vu.x), my = at * bf2f(vu.y);
        const float mz = at * bf2f(vu.z), mw = at * bf2f(vu.w);
        if (t == 0)      { a0.x += mx; a0.y += my; a0.z += mz; a0.w += mw; }
        else if (t == 1) { a1.x += mx; a1.y += my; a1.z += mz; a1.w += mw; }
        else if (t == 2) { a2.x += mx; a2.y += my; a2.z += mz; a2.w += mw; }
        else if (t == 3) { a3.x += mx; a3.y += my; a3.z += mz; a3.w += mw; }
        else             { a4.x += mx; a4.y += my; a4.z += mz; a4.w += mw; }
    }
    const size_t r = (size_t)tgt * NHEAD + h;
    unsigned short* base = Acat + r * (NTYPES * HDIM) + f0;
    ushort4 u;
    u.x = f2bf(a0.x); u.y = f2bf(a0.y); u.z = f2bf(a0.z); u.w = f2bf(a0.w);
    *(ushort4*)(base + 0 * HDIM) = u;
    u.x = f2bf(a1.x); u.y = f2bf(a1.y); u.z = f2bf(a1.z); u.w = f2bf(a1.w);
    *(ushort4*)(base + 1 * HDIM) = u;
    u.x = f2bf(a2.x); u.y = f2bf(a2.y); u.z = f2bf(a2.z); u.w = f2bf(a2.w);
    *(ushort4*)(base + 2 * HDIM) = u;
    u.x = f2bf(a3.x); u.y = f2bf(a3.y); u.z = f2bf(a3.z); u.w = f2bf(a3.w);
    *(ushort4*)(base + 3 * HDIM) = u;
    u.x = f2bf(a4.x); u.y = f2bf(a4.y); u.z = f2bf(a4.z); u.w = f2bf(a4.w);
    *(ushort4*)(base + 4 * HDIM) = u;
}

// ---- epilogue GEMM: aggV[120000,64] = gelu(Acat[120000,320](bf16) @ v_rel[320,64]) ----
__global__ __launch_bounds__(256) void gemm_cat(const unsigned short* __restrict__ A,
                                                const float* __restrict__ B,
                                                float* __restrict__ C) {
    __shared__ float As[16][68];
    __shared__ float Bs[16][68];
    const int row0 = blockIdx.x * 64;
    const int t = threadIdx.x;
    const int tx = t & 15, ty = t >> 4;
    const int lrow = t >> 2, lk4 = (t & 3) << 2;
    const int br = t >> 4, bc0 = (t & 15) << 2;
    float acc[4][4] = {};
    for (int kt = 0; kt < 320; kt += 16) {
        const ushort4 a4u = *(const ushort4*)(A + (size_t)(row0 + lrow) * 320 + kt + lk4);
        const float4 b4 = *(const float4*)(B + (size_t)(kt + br) * 64 + bc0);
        As[lk4 + 0][lrow] = bf2f(a4u.x);
        As[lk4 + 1][lrow] = bf2f(a4u.y);
        As[lk4 + 2][lrow] = bf2f(a4u.z);
        As[lk4 + 3][lrow] = bf2f(a4u.w);
        Bs[br][bc0 + 0] = b4.x; Bs[br][bc0 + 1] = b4.y;
        Bs[br][bc0 + 2] = b4.z; Bs[br][bc0 + 3] = b4.w;
        __syncthreads();
#pragma unroll
        for (int k = 0; k < 16; ++k) {
            const float4 av = *(const float4*)&As[k][ty << 2];
            const float4 bv = *(const float4*)&Bs[k][tx << 2];
            const float aa[4] = {av.x, av.y, av.z, av.w};
            const float bb[4] = {bv.x, bv.y, bv.z, bv.w};
#pragma unroll
            for (int i = 0; i < 4; ++i)
#pragma unroll
                for (int j = 0; j < 4; ++j)
                    acc[i][j] = fmaf(aa[i], bb[j], acc[i][j]);
        }
        __syncthreads();
    }
#pragma unroll
    for (int i = 0; i < 4; ++i) {
        const int r = row0 + (ty << 2) + i;
#pragma unroll
        for (int j = 0; j < 4; ++j) {
            const int c = (tx << 2) + j;
            const float v = acc[i][j];
            C[(size_t)r * 64 + c] = 0.5f * v * (1.f + erff(v * 0.7071067811865475f));
        }
    }
}

// ---- final f32 GEMM with fused skip blend: out = a*(aggV@W^T+b) + (1-a)*h ----
__global__ __launch_bounds__(256) void gemm_out(const float* __restrict__ A,
                                                const float* __restrict__ W,
                                                const float* __restrict__ bias,
                                                float* __restrict__ C,
                                                const float* __restrict__ hres,
                                                const float* __restrict__ skip) {
    __shared__ float As[16][68];
    __shared__ float Bs[16][68];
    const int row0 = blockIdx.x * 64, col0 = blockIdx.y * 64;
    const int t = threadIdx.x;
    const int tx = t & 15, ty = t >> 4;
    const int lrow = t >> 2, lk4 = (t & 3) << 2;
    float acc[4][4] = {};
    for (int kt = 0; kt < 256; kt += 16) {
        float4 a4 = make_float4(0.f, 0.f, 0.f, 0.f);
        const int ar = row0 + lrow;
        if (ar < N_NODES) a4 = *(const float4*)(A + (size_t)ar * 256 + kt + lk4);
        const float4 b4 = *(const float4*)(W + (size_t)(col0 + lrow) * 256 + kt + lk4);
        As[lk4 + 0][lrow] = a4.x; As[lk4 + 1][lrow] = a4.y;
        As[lk4 + 2][lrow] = a4.z; As[lk4 + 3][lrow] = a4.w;
        Bs[lk4 + 0][lrow] = b4.x; Bs[lk4 + 1][lrow] = b4.y;
        Bs[lk4 + 2][lrow] = b4.z; Bs[lk4 + 3][lrow] = b4.w;
        __syncthreads();
#pragma unroll
        for (int k = 0; k < 16; ++k) {
            const float4 av = *(const float4*)&As[k][ty << 2];
            const float4 bv = *(const float4*)&Bs[k][tx << 2];
            const float aa[4] = {av.x, av.y, av.z, av.w};
            const float bb[4] = {bv.x, bv.y, bv.z, bv.w};
#pragma unroll
            for (int i = 0; i < 4; ++i)
#pragma unroll
                for (int j = 0; j < 4; ++j)
                    acc[i][j] = fmaf(aa[i], bb[j], acc[i][j]);
        }
        __syncthreads();
    }
    const float s = skip[0];
    const float sa = 1.f / (1.f + expf(-s));
    const float sb = 1.f - sa;
#pragma unroll
    for (int i = 0; i < 4; ++i) {
        const int r = row0 + (ty << 2) + i;
        if (r >= N_NODES) continue;
#pragma unroll
        for (int j = 0; j < 4; ++j) {
            const int c = col0 + (tx << 2) + j;
            const float v = acc[i][j] + bias[c];
            C[(size_t)r * 256 + c] = sa * v + sb * hres[(size_t)r * 256 + c];
        }
    }
}

extern "C" void kernel_launch(void* const* d_in, const int* in_sizes, int n_in,
                              void* d_out, int out_size, void* d_ws, size_t ws_size,
                              hipStream_t stream) {
    const float* h      = (const float*)d_in[0];
    const int*   esrc   = (const int*)d_in[1];
    const int*   etgt   = (const int*)d_in[2];
    const float* kqv_w  = (const float*)d_in[3];
    const float* kqv_b  = (const float*)d_in[4];
    const float* out_w  = (const float*)d_in[5];
    const float* out_b  = (const float*)d_in[6];
    const float* k_rel  = (const float*)d_in[7];
    const float* v_rel  = (const float*)d_in[8];
    const float* skip   = (const float*)d_in[9];
    const float* p_rel  = (const float*)d_in[10];
    float* out = (float*)d_out;

    // workspace layout (float-sized slots):
    float* ws = (float*)d_ws;
    unsigned short* Ccat   = (unsigned short*)ws;            // 30000*1792 bf16 = 26,880,000 slots
    float*          alpha  = ws + 26880000;                  //    800,000
    float*          expsum = ws + 27680000;                  //    120,000
    int*            deg    = (int*)(ws + 27800000);          //     30,000
    int*            off    = (int*)(ws + 27830000);          //     30,000
    int*            cursor = (int*)(ws + 27860000);          //     30,000
    int*            perm   = (int*)(ws + 27890000);          //    200,000
    float*          aggV   = ws + 28090000;                  //  7,680,000
    unsigned short* Acat   = (unsigned short*)(ws + 35770000); // 120000*320 bf16 = 19,200,000 slots
    // aliased into the Acat region (dead once Ccat is computed; Acat written later):
    unsigned short* hb       = Acat;                          // 30000*256 bf16 = 3,840,000 slots
    unsigned short* Wcat     = (unsigned short*)(ws + 35770000 + 3840000);  // 229,376 slots
    float*          bias_cat = ws + 35770000 + 3840000 + 230000;            // 1,792
    // total: 54,970,000 float slots = 219.9 MB

    hipLaunchKernelGGL(init_kernel, dim3(512), dim3(256), 0, stream, expsum, deg);
    hipLaunchKernelGGL(hist_kernel, dim3(782), dim3(256), 0, stream, etgt, deg);
    hipLaunchKernelGGL(scan_kernel, dim3(1), dim3(1024), 0, stream, deg, off, cursor);
    hipLaunchKernelGGL(scatter_kernel, dim3(782), dim3(256), 0, stream, etgt, cursor, perm);
    hipLaunchKernelGGL(weight_prep, dim3(NCAT), dim3(256), 0, stream,
                       kqv_w, kqv_b, k_rel, p_rel, Wcat, bias_cat);
    hipLaunchKernelGGL(h2bf_kernel, dim3(7500), dim3(256), 0, stream, h, hb);
    hipLaunchKernelGGL(mfma_gemm, dim3(235, 14), dim3(256), 0, stream,
                       hb, Wcat, bias_cat, Ccat);
    hipLaunchKernelGGL(alpha_kernel, dim3(TE / 4), dim3(256), 0, stream,
                       Ccat, esrc, etgt, alpha, expsum);
    hipLaunchKernelGGL(accumulate_kernel, dim3(N_NODES / 4), dim3(256), 0, stream,
                       Ccat, esrc, off, perm, alpha, expsum, Acat);
    hipLaunchKernelGGL(gemm_cat, dim3(120000 / 64), dim3(256), 0, stream,
                       Acat, v_rel, aggV);
    hipLaunchKernelGGL(gemm_out, dim3(469, 4), dim3(256), 0, stream,
                       aggV, out_w, out_b, out, h, skip);
}

// Round 5
// 303.082 us; speedup vs baseline: 3.6824x; 1.2705x over previous
//
#include <hip/hip_runtime.h>
#include <hip/hip_bf16.h>
#include <math.h>

#define N_NODES 30000
#define NHEAD   4
#define HDIM    64
#define NTYPES  5
#define EPT     40000
#define TE      (NTYPES * EPT)
#define KDIM    256
#define NCAT    1792   // 1280 Ktil | 256 Q | 256 V

typedef __attribute__((ext_vector_type(8))) short short8;
typedef __attribute__((ext_vector_type(4))) float f32x4;

__device__ __forceinline__ unsigned short f2bf(float f) {
    __hip_bfloat16 h = __float2bfloat16(f);
    return *reinterpret_cast<unsigned short*>(&h);
}
__device__ __forceinline__ float bf2f(unsigned short u) {
    return __uint_as_float((unsigned)u << 16);
}

// ---- init: zero expsum and deg ----
__global__ __launch_bounds__(256) void init_kernel(float* __restrict__ expsum,
                                                   int* __restrict__ deg) {
    const int stride = gridDim.x * blockDim.x;
    const int gid = blockIdx.x * blockDim.x + threadIdx.x;
    for (int i = gid; i < N_NODES * NHEAD; i += stride) expsum[i] = 0.f;
    for (int i = gid; i < N_NODES; i += stride) deg[i] = 0;
}

// ---- CSR build: histogram ----
__global__ __launch_bounds__(256) void hist_kernel(const int* __restrict__ etgt,
                                                   int* __restrict__ deg) {
    const int stride = gridDim.x * blockDim.x;
    for (int i = blockIdx.x * blockDim.x + threadIdx.x; i < TE; i += stride)
        atomicAdd(&deg[etgt[i]], 1);
}

// ---- CSR build: single-block exclusive scan over 30000 degrees ----
__global__ __launch_bounds__(1024) void scan_kernel(const int* __restrict__ deg,
                                                    int* __restrict__ off,
                                                    int* __restrict__ cursor) {
    __shared__ int sums[1024];
    const int t = threadIdx.x;
    int local[30];
    int s = 0;
    const int base = t * 30;
#pragma unroll
    for (int j = 0; j < 30; ++j) {
        const int idx = base + j;
        const int d = (idx < N_NODES) ? deg[idx] : 0;
        local[j] = d;
        s += d;
    }
    sums[t] = s;
    __syncthreads();
    for (int d = 1; d < 1024; d <<= 1) {
        const int v = (t >= d) ? sums[t - d] : 0;
        __syncthreads();
        sums[t] += v;
        __syncthreads();
    }
    int run = (t > 0) ? sums[t - 1] : 0;
#pragma unroll
    for (int j = 0; j < 30; ++j) {
        const int idx = base + j;
        if (idx < N_NODES) {
            off[idx] = run;
            cursor[idx] = run;
            run += local[j];
        }
    }
}

// ---- CSR build: scatter edge ids into per-target buckets ----
__global__ __launch_bounds__(256) void scatter_kernel(const int* __restrict__ etgt,
                                                      int* __restrict__ cursor,
                                                      int* __restrict__ perm) {
    const int stride = gridDim.x * blockDim.x;
    for (int e = blockIdx.x * blockDim.x + threadIdx.x; e < TE; e += stride) {
        const int pos = atomicAdd(&cursor[etgt[e]], 1);
        perm[pos] = e;
    }
}

// ---- weight prep: Wcat[1792,256] bf16 (+bias_cat f32) ----
__global__ __launch_bounds__(256) void weight_prep(const float* __restrict__ kqv_w,
                                                   const float* __restrict__ kqv_b,
                                                   const float* __restrict__ k_rel,
                                                   const float* __restrict__ p_rel,
                                                   unsigned short* __restrict__ Wcat,
                                                   float* __restrict__ bias_cat) {
    const int r = blockIdx.x;
    const int f = threadIdx.x;
    if (r < 1280) {
        const int t = r >> 8, h = (r >> 6) & 3, d = r & 63;
        const float sc = 0.125f * p_rel[t * NHEAD + h];
        float acc = 0.f;
#pragma unroll
        for (int fp = 0; fp < 64; ++fp)
            acc = fmaf(kqv_w[(size_t)(h * 64 + fp) * 256 + f], k_rel[t * 4096 + fp * 64 + d], acc);
        Wcat[(size_t)r * 256 + f] = f2bf(acc * sc);
        if (f == 0) {
            float b = 0.f;
#pragma unroll
            for (int fp = 0; fp < 64; ++fp)
                b = fmaf(kqv_b[h * 64 + fp], k_rel[t * 4096 + fp * 64 + d], b);
            bias_cat[r] = b * sc;
        }
    } else {
        const int src_row = r - 1024;  // 1280->256 (Q), 1536->512 (V)
        Wcat[(size_t)r * 256 + f] = f2bf(kqv_w[(size_t)src_row * 256 + f]);
        if (f == 0) bias_cat[r] = kqv_b[src_row];
    }
}

// ---- h -> bf16 ----
__global__ __launch_bounds__(256) void h2bf_kernel(const float* __restrict__ h,
                                                   unsigned short* __restrict__ hb) {
    const int i = blockIdx.x * 256 + threadIdx.x;
    if (i >= N_NODES * KDIM / 4) return;
    const float4 v = ((const float4*)h)[i];
    ushort4 u;
    u.x = f2bf(v.x); u.y = f2bf(v.y); u.z = f2bf(v.z); u.w = f2bf(v.w);
    ((ushort4*)hb)[i] = u;
}

// ---- v_rel[320,64] -> vrelT[64,320] bf16 ----
__global__ __launch_bounds__(320) void vrelT_prep(const float* __restrict__ v_rel,
                                                  unsigned short* __restrict__ vrelT) {
    const int f = blockIdx.x;        // 0..63 output row (col of v_rel)
    const int k = threadIdx.x;       // 0..319 = t*64+d
    vrelT[f * 320 + k] = f2bf(v_rel[(k >> 6) * 4096 + (k & 63) * 64 + f]);
}

// ---- out_w -> bf16 ----
__global__ __launch_bounds__(256) void owb_prep(const float* __restrict__ out_w,
                                                unsigned short* __restrict__ Wob) {
    const int i = blockIdx.x * 256 + threadIdx.x;
    Wob[i] = f2bf(out_w[i]);
}

// ---- MFMA GEMM: Ccat[30000,1792](bf16) = hb[30000,256] @ Wcat^T + bias_cat ----
// 128x128 tile, BK=32, 4 waves (2x2). LDS rows padded to 40 bf16.
__global__ __launch_bounds__(256) void mfma_gemm(const unsigned short* __restrict__ hb,
                                                 const unsigned short* __restrict__ Wcat,
                                                 const float* __restrict__ bias_cat,
                                                 unsigned short* __restrict__ Ccat) {
    __shared__ unsigned short As[128 * 40];
    __shared__ unsigned short Bs[128 * 40];
    const int brow0 = blockIdx.x * 128;
    const int bcol0 = blockIdx.y * 128;
    const int t = threadIdx.x;
    const int wid = t >> 6, lane = t & 63;
    const int wr = wid >> 1, wc = wid & 1;
    const int lrow = lane & 15, kb = lane >> 4;
    const int r0 = t >> 2, q0 = t & 3;
    const int r1 = (t + 256) >> 2, q1 = t & 3;

    f32x4 acc[4][4];
#pragma unroll
    for (int m = 0; m < 4; ++m)
#pragma unroll
        for (int n = 0; n < 4; ++n) acc[m][n] = (f32x4)0.f;

    for (int kt = 0; kt < KDIM; kt += 32) {
        const int ar0 = min(brow0 + r0, N_NODES - 1);
        const int ar1 = min(brow0 + r1, N_NODES - 1);
        const uint4 a0 = *(const uint4*)(hb + (size_t)ar0 * KDIM + kt + q0 * 8);
        const uint4 a1 = *(const uint4*)(hb + (size_t)ar1 * KDIM + kt + q1 * 8);
        const uint4 b0 = *(const uint4*)(Wcat + (size_t)(bcol0 + r0) * KDIM + kt + q0 * 8);
        const uint4 b1 = *(const uint4*)(Wcat + (size_t)(bcol0 + r1) * KDIM + kt + q1 * 8);
        __syncthreads();
        *(uint4*)&As[r0 * 40 + q0 * 8] = a0;
        *(uint4*)&As[r1 * 40 + q1 * 8] = a1;
        *(uint4*)&Bs[r0 * 40 + q0 * 8] = b0;
        *(uint4*)&Bs[r1 * 40 + q1 * 8] = b1;
        __syncthreads();
        short8 af[4], bf_[4];
#pragma unroll
        for (int m = 0; m < 4; ++m)
            af[m] = *(const short8*)&As[(wr * 64 + m * 16 + lrow) * 40 + kb * 8];
#pragma unroll
        for (int n = 0; n < 4; ++n)
            bf_[n] = *(const short8*)&Bs[(wc * 64 + n * 16 + lrow) * 40 + kb * 8];
#pragma unroll
        for (int m = 0; m < 4; ++m)
#pragma unroll
            for (int n = 0; n < 4; ++n)
                acc[m][n] = __builtin_amdgcn_mfma_f32_16x16x32_bf16(af[m], bf_[n], acc[m][n], 0, 0, 0);
    }

    float bias4[4];
#pragma unroll
    for (int n = 0; n < 4; ++n) bias4[n] = bias_cat[bcol0 + wc * 64 + n * 16 + lrow];
#pragma unroll
    for (int m = 0; m < 4; ++m) {
        const int gr0 = brow0 + wr * 64 + m * 16 + kb * 4;
#pragma unroll
        for (int v = 0; v < 4; ++v) {
            const int grow = gr0 + v;
            if (grow < N_NODES) {
#pragma unroll
                for (int n = 0; n < 4; ++n) {
                    const int gcol = bcol0 + wc * 64 + n * 16 + lrow;
                    Ccat[(size_t)grow * NCAT + gcol] = f2bf(acc[m][n][v] + bias4[n]);
                }
            }
        }
    }
}

// ---- MFMA epilogue GEMM: aggVb[120000,64](bf16) = gelu(Acat[120000,320] @ vrelT^T) ----
// 256-row x 64-col block, 4 waves stacked on rows; K=320 in 10 steps of 32.
__global__ __launch_bounds__(256) void gemm_cat_mfma(const unsigned short* __restrict__ Acat,
                                                     const unsigned short* __restrict__ vrelT,
                                                     unsigned short* __restrict__ aggVb) {
    __shared__ unsigned short As[256 * 40];
    __shared__ unsigned short Bs[64 * 40];
    const int brow0 = blockIdx.x * 256;
    const int t = threadIdx.x;
    const int wid = t >> 6, lane = t & 63;
    const int lrow = lane & 15, kb = lane >> 4;
    const int r0 = t >> 2, q0 = (t & 3) * 8;

    f32x4 acc[4][4];
#pragma unroll
    for (int m = 0; m < 4; ++m)
#pragma unroll
        for (int n = 0; n < 4; ++n) acc[m][n] = (f32x4)0.f;

    for (int kt = 0; kt < 320; kt += 32) {
        uint4 a[4];
#pragma unroll
        for (int i = 0; i < 4; ++i) {
            const int row = min(brow0 + r0 + 64 * i, 120000 - 1);
            a[i] = *(const uint4*)(Acat + (size_t)row * 320 + kt + q0);
        }
        const uint4 b0 = *(const uint4*)(vrelT + (size_t)r0 * 320 + kt + q0);
        __syncthreads();
#pragma unroll
        for (int i = 0; i < 4; ++i)
            *(uint4*)&As[(r0 + 64 * i) * 40 + q0] = a[i];
        *(uint4*)&Bs[r0 * 40 + q0] = b0;
        __syncthreads();
        short8 af[4], bf_[4];
#pragma unroll
        for (int m = 0; m < 4; ++m)
            af[m] = *(const short8*)&As[(wid * 64 + m * 16 + lrow) * 40 + kb * 8];
#pragma unroll
        for (int n = 0; n < 4; ++n)
            bf_[n] = *(const short8*)&Bs[(n * 16 + lrow) * 40 + kb * 8];
#pragma unroll
        for (int m = 0; m < 4; ++m)
#pragma unroll
            for (int n = 0; n < 4; ++n)
                acc[m][n] = __builtin_amdgcn_mfma_f32_16x16x32_bf16(af[m], bf_[n], acc[m][n], 0, 0, 0);
    }

#pragma unroll
    for (int m = 0; m < 4; ++m) {
        const int gr0 = brow0 + wid * 64 + m * 16 + kb * 4;
#pragma unroll
        for (int v = 0; v < 4; ++v) {
            const int grow = gr0 + v;
            if (grow < 120000) {
#pragma unroll
                for (int n = 0; n < 4; ++n) {
                    const int gcol = n * 16 + lrow;
                    const float x = acc[m][n][v];
                    const float g = 0.5f * x * (1.f + erff(x * 0.7071067811865475f));
                    aggVb[(size_t)grow * 64 + gcol] = f2bf(g);
                }
            }
        }
    }
}

// ---- MFMA out GEMM: out[30000,256] = sa*(aggVb @ Wob^T + out_b) + sb*h ----
__global__ __launch_bounds__(256) void gemm_out_mfma(const unsigned short* __restrict__ A,
                                                     const unsigned short* __restrict__ Wob,
                                                     const float* __restrict__ bias,
                                                     float* __restrict__ C,
                                                     const float* __restrict__ hres,
                                                     const float* __restrict__ skip) {
    __shared__ unsigned short As[128 * 40];
    __shared__ unsigned short Bs[128 * 40];
    const int brow0 = blockIdx.x * 128;
    const int bcol0 = blockIdx.y * 128;
    const int t = threadIdx.x;
    const int wid = t >> 6, lane = t & 63;
    const int wr = wid >> 1, wc = wid & 1;
    const int lrow = lane & 15, kb = lane >> 4;
    const int r0 = t >> 2, q0 = t & 3;
    const int r1 = (t + 256) >> 2, q1 = t & 3;

    f32x4 acc[4][4];
#pragma unroll
    for (int m = 0; m < 4; ++m)
#pragma unroll
        for (int n = 0; n < 4; ++n) acc[m][n] = (f32x4)0.f;

    for (int kt = 0; kt < 256; kt += 32) {
        const int ar0 = min(brow0 + r0, N_NODES - 1);
        const int ar1 = min(brow0 + r1, N_NODES - 1);
        const uint4 a0 = *(const uint4*)(A + (size_t)ar0 * 256 + kt + q0 * 8);
        const uint4 a1 = *(const uint4*)(A + (size_t)ar1 * 256 + kt + q1 * 8);
        const uint4 b0 = *(const uint4*)(Wob + (size_t)(bcol0 + r0) * 256 + kt + q0 * 8);
        const uint4 b1 = *(const uint4*)(Wob + (size_t)(bcol0 + r1) * 256 + kt + q1 * 8);
        __syncthreads();
        *(uint4*)&As[r0 * 40 + q0 * 8] = a0;
        *(uint4*)&As[r1 * 40 + q1 * 8] = a1;
        *(uint4*)&Bs[r0 * 40 + q0 * 8] = b0;
        *(uint4*)&Bs[r1 * 40 + q1 * 8] = b1;
        __syncthreads();
        short8 af[4], bf_[4];
#pragma unroll
        for (int m = 0; m < 4; ++m)
            af[m] = *(const short8*)&As[(wr * 64 + m * 16 + lrow) * 40 + kb * 8];
#pragma unroll
        for (int n = 0; n < 4; ++n)
            bf_[n] = *(const short8*)&Bs[(wc * 64 + n * 16 + lrow) * 40 + kb * 8];
#pragma unroll
        for (int m = 0; m < 4; ++m)
#pragma unroll
            for (int n = 0; n < 4; ++n)
                acc[m][n] = __builtin_amdgcn_mfma_f32_16x16x32_bf16(af[m], bf_[n], acc[m][n], 0, 0, 0);
    }

    const float s = skip[0];
    const float sa = 1.f / (1.f + expf(-s));
    const float sb = 1.f - sa;
    float bias4[4];
#pragma unroll
    for (int n = 0; n < 4; ++n) bias4[n] = bias[bcol0 + wc * 64 + n * 16 + lrow];
#pragma unroll
    for (int m = 0; m < 4; ++m) {
        const int gr0 = brow0 + wr * 64 + m * 16 + kb * 4;
#pragma unroll
        for (int v = 0; v < 4; ++v) {
            const int grow = gr0 + v;
            if (grow < N_NODES) {
#pragma unroll
                for (int n = 0; n < 4; ++n) {
                    const int gcol = bcol0 + wc * 64 + n * 16 + lrow;
                    const float val = acc[m][n][v] + bias4[n];
                    C[(size_t)grow * 256 + gcol] = sa * val + sb * hres[(size_t)grow * 256 + gcol];
                }
            }
        }
    }
}

// ---- alpha: one wave per edge; exp + expsum atomic fused (scale/p_rel pre-folded) ----
__global__ __launch_bounds__(256) void alpha_kernel(const unsigned short* __restrict__ Ccat,
                                                    const int* __restrict__ esrc,
                                                    const int* __restrict__ etgt,
                                                    float* __restrict__ alpha_exp,
                                                    float* __restrict__ expsum) {
    const int wid = threadIdx.x >> 6, lane = threadIdx.x & 63;
    const int e = (blockIdx.x << 2) + wid;
    const int t = e / EPT;
    const int src = esrc[e], tgt = etgt[e];
    const int h = lane >> 4, f0 = (lane & 15) << 2;
    const ushort4 qu = *(const ushort4*)(Ccat + (size_t)tgt * NCAT + 1280 + h * 64 + f0);
    const ushort4 ku = *(const ushort4*)(Ccat + (size_t)src * NCAT + (t * 4 + h) * 64 + f0);
    float part = bf2f(qu.x) * bf2f(ku.x) + bf2f(qu.y) * bf2f(ku.y)
               + bf2f(qu.z) * bf2f(ku.z) + bf2f(qu.w) * bf2f(ku.w);
    part += __shfl_xor(part, 1);
    part += __shfl_xor(part, 2);
    part += __shfl_xor(part, 4);
    part += __shfl_xor(part, 8);
    if ((lane & 15) == 0) {
        const float ex = expf(part);
        alpha_exp[(size_t)e * NHEAD + h] = ex;
        atomicAdd(&expsum[tgt * NHEAD + h], ex);
    }
}

// ---- accumulate: one wave per target; Acat[tgt*4+h][t*64+d] = sum_e attn * V[src][h][d] (bf16) ----
__global__ __launch_bounds__(256) void accumulate_kernel(const unsigned short* __restrict__ Ccat,
                                                         const int* __restrict__ esrc,
                                                         const int* __restrict__ off,
                                                         const int* __restrict__ perm,
                                                         const float* __restrict__ alpha_exp,
                                                         const float* __restrict__ expsum,
                                                         unsigned short* __restrict__ Acat) {
    const int wid = threadIdx.x >> 6, lane = threadIdx.x & 63;
    const int tgt = (blockIdx.x << 2) + wid;
    const int h = lane >> 4, f0 = (lane & 15) << 2;
    const int off0 = off[tgt];
    const int off1 = (tgt == N_NODES - 1) ? TE : off[tgt + 1];
    const int deg = off1 - off0;
    const float inv_es = 1.f / (expsum[tgt * NHEAD + h] + 1e-16f);
    float4 a0 = make_float4(0, 0, 0, 0), a1 = a0, a2 = a0, a3 = a0, a4 = a0;
    for (int i = 0; i < deg; ++i) {
        const int e = perm[off0 + i];
        const int t = e / EPT;  // uniform across wave
        const int src = esrc[e];
        const float at = alpha_exp[(size_t)e * NHEAD + h] * inv_es;
        const ushort4 vu = *(const ushort4*)(Ccat + (size_t)src * NCAT + 1536 + (h << 6) + f0);
        const float mx = at * bf2f(vu.x), my = at * bf2f(vu.y);
        const float mz = at * bf2f(vu.z), mw = at * bf2f(vu.w);
        if (t == 0)      { a0.x += mx; a0.y += my; a0.z += mz; a0.w += mw; }
        else if (t == 1) { a1.x += mx; a1.y += my; a1.z += mz; a1.w += mw; }
        else if (t == 2) { a2.x += mx; a2.y += my; a2.z += mz; a2.w += mw; }
        else if (t == 3) { a3.x += mx; a3.y += my; a3.z += mz; a3.w += mw; }
        else             { a4.x += mx; a4.y += my; a4.z += mz; a4.w += mw; }
    }
    const size_t r = (size_t)tgt * NHEAD + h;
    unsigned short* base = Acat + r * (NTYPES * HDIM) + f0;
    ushort4 u;
    u.x = f2bf(a0.x); u.y = f2bf(a0.y); u.z = f2bf(a0.z); u.w = f2bf(a0.w);
    *(ushort4*)(base + 0 * HDIM) = u;
    u.x = f2bf(a1.x); u.y = f2bf(a1.y); u.z = f2bf(a1.z); u.w = f2bf(a1.w);
    *(ushort4*)(base + 1 * HDIM) = u;
    u.x = f2bf(a2.x); u.y = f2bf(a2.y); u.z = f2bf(a2.z); u.w = f2bf(a2.w);
    *(ushort4*)(base + 2 * HDIM) = u;
    u.x = f2bf(a3.x); u.y = f2bf(a3.y); u.z = f2bf(a3.z); u.w = f2bf(a3.w);
    *(ushort4*)(base + 3 * HDIM) = u;
    u.x = f2bf(a4.x); u.y = f2bf(a4.y); u.z = f2bf(a4.z); u.w = f2bf(a4.w);
    *(ushort4*)(base + 4 * HDIM) = u;
}

extern "C" void kernel_launch(void* const* d_in, const int* in_sizes, int n_in,
                              void* d_out, int out_size, void* d_ws, size_t ws_size,
                              hipStream_t stream) {
    const float* h      = (const float*)d_in[0];
    const int*   esrc   = (const int*)d_in[1];
    const int*   etgt   = (const int*)d_in[2];
    const float* kqv_w  = (const float*)d_in[3];
    const float* kqv_b  = (const float*)d_in[4];
    const float* out_w  = (const float*)d_in[5];
    const float* out_b  = (const float*)d_in[6];
    const float* k_rel  = (const float*)d_in[7];
    const float* v_rel  = (const float*)d_in[8];
    const float* skip   = (const float*)d_in[9];
    const float* p_rel  = (const float*)d_in[10];
    float* out = (float*)d_out;

    // workspace layout (float-sized slots):
    float* ws = (float*)d_ws;
    unsigned short* Ccat     = (unsigned short*)ws;                 // 53,760,000 ushorts = 26,880,000 slots [0 .. 26.88M)
    float*          alpha    = ws + 26880000;                       //    800,000  -> 27.68M
    float*          expsum   = ws + 27680000;                       //    120,000  -> 27.80M
    int*            deg      = (int*)(ws + 27800000);               //     30,000  -> 27.83M
    int*            off      = (int*)(ws + 27830000);               //     30,000  -> 27.86M
    int*            cursor   = (int*)(ws + 27860000);               //     30,000  -> 27.89M
    int*            perm     = (int*)(ws + 27890000);               //    200,000  -> 28.09M
    unsigned short* aggVb    = (unsigned short*)(ws + 28090000);    // 7,680,000 ushorts = 3,840,000 slots -> 31.93M
    unsigned short* Acat     = (unsigned short*)(ws + 31930000);    // 38,400,000 ushorts = 19,200,000 slots -> 51.13M
    // LATE-READ buffers (consumed AFTER Acat is written) -> must live past Acat's end:
    unsigned short* vrelT    = (unsigned short*)(ws + 51130000);    // 20,480 ushorts = 10,240 slots -> 51,140,240
    unsigned short* Wob      = (unsigned short*)(ws + 51140240);    // 65,536 ushorts = 32,768 slots -> 51,173,008
    // EARLY-DEAD aliases inside Acat's span (read only BEFORE accumulate_kernel writes Acat):
    unsigned short* hb       = (unsigned short*)(ws + 41530000);    // 7,680,000 ushorts -> ends 45.37M
    unsigned short* Wcat     = (unsigned short*)(ws + 45370000);    // 458,752 ushorts -> ends 45.60M
    float*          bias_cat = ws + 45600000;                       //      1,792 -> ends 45,601,792 (< 51.13M ok)
    // total footprint: 51,173,008 float slots = 204.7 MB (round 3 proved >= 219.9 MB available)

    hipLaunchKernelGGL(init_kernel, dim3(512), dim3(256), 0, stream, expsum, deg);
    hipLaunchKernelGGL(hist_kernel, dim3(782), dim3(256), 0, stream, etgt, deg);
    hipLaunchKernelGGL(scan_kernel, dim3(1), dim3(1024), 0, stream, deg, off, cursor);
    hipLaunchKernelGGL(scatter_kernel, dim3(782), dim3(256), 0, stream, etgt, cursor, perm);
    hipLaunchKernelGGL(weight_prep, dim3(NCAT), dim3(256), 0, stream,
                       kqv_w, kqv_b, k_rel, p_rel, Wcat, bias_cat);
    hipLaunchKernelGGL(h2bf_kernel, dim3(7500), dim3(256), 0, stream, h, hb);
    hipLaunchKernelGGL(vrelT_prep, dim3(64), dim3(320), 0, stream, v_rel, vrelT);
    hipLaunchKernelGGL(owb_prep, dim3(256), dim3(256), 0, stream, out_w, Wob);
    hipLaunchKernelGGL(mfma_gemm, dim3(235, 14), dim3(256), 0, stream,
                       hb, Wcat, bias_cat, Ccat);
    hipLaunchKernelGGL(alpha_kernel, dim3(TE / 4), dim3(256), 0, stream,
                       Ccat, esrc, etgt, alpha, expsum);
    hipLaunchKernelGGL(accumulate_kernel, dim3(N_NODES / 4), dim3(256), 0, stream,
                       Ccat, esrc, off, perm, alpha, expsum, Acat);
    hipLaunchKernelGGL(gemm_cat_mfma, dim3(469), dim3(256), 0, stream,
                       Acat, vrelT, aggVb);
    hipLaunchKernelGGL(gemm_out_mfma, dim3(235, 2), dim3(256), 0, stream,
                       aggVb, Wob, out_b, out, h, skip);
}

// Round 6
// 269.865 us; speedup vs baseline: 4.1356x; 1.1231x over previous
//
#include <hip/hip_runtime.h>
#include <hip/hip_bf16.h>
#include <math.h>

#define N_NODES 30000
#define NHEAD   4
#define HDIM    64
#define NTYPES  5
#define EPT     40000
#define TE      (NTYPES * EPT)
#define KDIM    256
#define NCAT    1792   // 1280 Ktil | 256 Q | 256 V

typedef __attribute__((ext_vector_type(8))) short short8;
typedef __attribute__((ext_vector_type(4))) float f32x4;

__device__ __forceinline__ unsigned short f2bf(float f) {
    __hip_bfloat16 h = __float2bfloat16(f);
    return *reinterpret_cast<unsigned short*>(&h);
}
__device__ __forceinline__ float bf2f(unsigned short u) {
    return __uint_as_float((unsigned)u << 16);
}

// async global->LDS, 16B per lane. LDS dest is wave-uniform base + lane*16 (linear).
__device__ __forceinline__ void gload16(const unsigned short* g, unsigned short* l) {
    __builtin_amdgcn_global_load_lds((const __attribute__((address_space(1))) void*)g,
                                     (__attribute__((address_space(3))) void*)l, 16, 0, 0);
}

// ---- init: zero deg ----
__global__ __launch_bounds__(256) void init_kernel(int* __restrict__ deg) {
    const int gid = blockIdx.x * blockDim.x + threadIdx.x;
    if (gid < N_NODES) deg[gid] = 0;
}

// ---- CSR build: histogram ----
__global__ __launch_bounds__(256) void hist_kernel(const int* __restrict__ etgt,
                                                   int* __restrict__ deg) {
    const int stride = gridDim.x * blockDim.x;
    for (int i = blockIdx.x * blockDim.x + threadIdx.x; i < TE; i += stride)
        atomicAdd(&deg[etgt[i]], 1);
}

// ---- CSR build: single-block exclusive scan over 30000 degrees ----
__global__ __launch_bounds__(1024) void scan_kernel(const int* __restrict__ deg,
                                                    int* __restrict__ off,
                                                    int* __restrict__ cursor) {
    __shared__ int sums[1024];
    const int t = threadIdx.x;
    int local[30];
    int s = 0;
    const int base = t * 30;
#pragma unroll
    for (int j = 0; j < 30; ++j) {
        const int idx = base + j;
        const int d = (idx < N_NODES) ? deg[idx] : 0;
        local[j] = d;
        s += d;
    }
    sums[t] = s;
    __syncthreads();
    for (int d = 1; d < 1024; d <<= 1) {
        const int v = (t >= d) ? sums[t - d] : 0;
        __syncthreads();
        sums[t] += v;
        __syncthreads();
    }
    int run = (t > 0) ? sums[t - 1] : 0;
#pragma unroll
    for (int j = 0; j < 30; ++j) {
        const int idx = base + j;
        if (idx < N_NODES) {
            off[idx] = run;
            cursor[idx] = run;
            run += local[j];
        }
    }
}

// ---- CSR build: scatter edge ids into per-target buckets ----
__global__ __launch_bounds__(256) void scatter_kernel(const int* __restrict__ etgt,
                                                      int* __restrict__ cursor,
                                                      int* __restrict__ perm) {
    const int stride = gridDim.x * blockDim.x;
    for (int e = blockIdx.x * blockDim.x + threadIdx.x; e < TE; e += stride) {
        const int pos = atomicAdd(&cursor[etgt[e]], 1);
        perm[pos] = e;
    }
}

// ---- weight prep: Wcat[1792,256] bf16 (+bias_cat f32) ----
__global__ __launch_bounds__(256) void weight_prep(const float* __restrict__ kqv_w,
                                                   const float* __restrict__ kqv_b,
                                                   const float* __restrict__ k_rel,
                                                   const float* __restrict__ p_rel,
                                                   unsigned short* __restrict__ Wcat,
                                                   float* __restrict__ bias_cat) {
    const int r = blockIdx.x;
    const int f = threadIdx.x;
    if (r < 1280) {
        const int t = r >> 8, h = (r >> 6) & 3, d = r & 63;
        const float sc = 0.125f * p_rel[t * NHEAD + h];
        float acc = 0.f;
#pragma unroll
        for (int fp = 0; fp < 64; ++fp)
            acc = fmaf(kqv_w[(size_t)(h * 64 + fp) * 256 + f], k_rel[t * 4096 + fp * 64 + d], acc);
        Wcat[(size_t)r * 256 + f] = f2bf(acc * sc);
        if (f == 0) {
            float b = 0.f;
#pragma unroll
            for (int fp = 0; fp < 64; ++fp)
                b = fmaf(kqv_b[h * 64 + fp], k_rel[t * 4096 + fp * 64 + d], b);
            bias_cat[r] = b * sc;
        }
    } else {
        const int src_row = r - 1024;  // 1280->256 (Q), 1536->512 (V)
        Wcat[(size_t)r * 256 + f] = f2bf(kqv_w[(size_t)src_row * 256 + f]);
        if (f == 0) bias_cat[r] = kqv_b[src_row];
    }
}

// ---- h -> bf16 ----
__global__ __launch_bounds__(256) void h2bf_kernel(const float* __restrict__ h,
                                                   unsigned short* __restrict__ hb) {
    const int i = blockIdx.x * 256 + threadIdx.x;
    if (i >= N_NODES * KDIM / 4) return;
    const float4 v = ((const float4*)h)[i];
    ushort4 u;
    u.x = f2bf(v.x); u.y = f2bf(v.y); u.z = f2bf(v.z); u.w = f2bf(v.w);
    ((ushort4*)hb)[i] = u;
}

// ---- v_rel[320,64] -> vrelT[64,320] bf16 ----
__global__ __launch_bounds__(320) void vrelT_prep(const float* __restrict__ v_rel,
                                                  unsigned short* __restrict__ vrelT) {
    const int f = blockIdx.x;        // 0..63 output row (col of v_rel)
    const int k = threadIdx.x;       // 0..319 = t*64+d
    vrelT[f * 320 + k] = f2bf(v_rel[(k >> 6) * 4096 + (k & 63) * 64 + f]);
}

// ---- out_w -> bf16 ----
__global__ __launch_bounds__(256) void owb_prep(const float* __restrict__ out_w,
                                                unsigned short* __restrict__ Wob) {
    const int i = blockIdx.x * 256 + threadIdx.x;
    Wob[i] = f2bf(out_w[i]);
}

// ---- MFMA GEMM: Ccat[30000,1792](bf16) = hb[30000,256] @ Wcat^T + bias_cat ----
// 128x128 tile, BK=32, 4 waves (2x2). global_load_lds(16B) staging into LINEAR
// [128][32] LDS; 16B-chunk XOR swizzle c^=((row>>1)&3) applied on the GLOBAL
// source (DMA dest is linear) and on the ds_read address (rule #21: both sides).
__global__ __launch_bounds__(256) void mfma_gemm(const unsigned short* __restrict__ hb,
                                                 const unsigned short* __restrict__ Wcat,
                                                 const float* __restrict__ bias_cat,
                                                 unsigned short* __restrict__ Ccat) {
    __shared__ unsigned short As[128 * 32];
    __shared__ unsigned short Bs[128 * 32];
    const int brow0 = blockIdx.x * 128;
    const int bcol0 = blockIdx.y * 128;
    const int t = threadIdx.x;
    const int wid = t >> 6, lane = t & 63;
    const int wr = wid >> 1, wc = wid & 1;
    const int lrow = lane & 15, kb = lane >> 4;
    // staging: lane l fills LDS chunk (row l>>2, chunk l&3) <- global chunk (l&3)^((l>>3)&3)
    const int srow = lane >> 2;
    const int schunk = ((lane & 3) ^ ((lane >> 3) & 3)) * 8;   // ushort offset in row
    // swizzled read chunk: kb ^ ((row>>1)&3) with row=16k+lrow -> kb ^ ((lrow>>1)&3)
    const int rchunk = (kb ^ ((lrow >> 1) & 3)) * 8;

    const int arow0 = min(brow0 + wid * 16 + srow, N_NODES - 1);
    const int arow1 = min(brow0 + 64 + wid * 16 + srow, N_NODES - 1);
    const int brw0 = bcol0 + wid * 16 + srow;        // always < 1792
    const int brw1 = bcol0 + 64 + wid * 16 + srow;

    f32x4 acc[4][4];
#pragma unroll
    for (int m = 0; m < 4; ++m)
#pragma unroll
        for (int n = 0; n < 4; ++n) acc[m][n] = (f32x4)0.f;

    for (int kt = 0; kt < KDIM; kt += 32) {
        gload16(hb + (size_t)arow0 * KDIM + kt + schunk, As + wid * 512);
        gload16(hb + (size_t)arow1 * KDIM + kt + schunk, As + 2048 + wid * 512);
        gload16(Wcat + (size_t)brw0 * KDIM + kt + schunk, Bs + wid * 512);
        gload16(Wcat + (size_t)brw1 * KDIM + kt + schunk, Bs + 2048 + wid * 512);
        __syncthreads();  // drains vmcnt(0): DMA landed, all waves synced
        short8 af[4], bfr[4];
#pragma unroll
        for (int m = 0; m < 4; ++m)
            af[m] = *(const short8*)&As[(wr * 64 + m * 16 + lrow) * 32 + rchunk];
#pragma unroll
        for (int n = 0; n < 4; ++n)
            bfr[n] = *(const short8*)&Bs[(wc * 64 + n * 16 + lrow) * 32 + rchunk];
#pragma unroll
        for (int m = 0; m < 4; ++m)
#pragma unroll
            for (int n = 0; n < 4; ++n)
                acc[m][n] = __builtin_amdgcn_mfma_f32_16x16x32_bf16(af[m], bfr[n], acc[m][n], 0, 0, 0);
        __syncthreads();  // all ds_reads done before next iteration's DMA lands
    }

    float bias4[4];
#pragma unroll
    for (int n = 0; n < 4; ++n) bias4[n] = bias_cat[bcol0 + wc * 64 + n * 16 + lrow];
#pragma unroll
    for (int m = 0; m < 4; ++m) {
        const int gr0 = brow0 + wr * 64 + m * 16 + kb * 4;
#pragma unroll
        for (int v = 0; v < 4; ++v) {
            const int grow = gr0 + v;
            if (grow < N_NODES) {
#pragma unroll
                for (int n = 0; n < 4; ++n) {
                    const int gcol = bcol0 + wc * 64 + n * 16 + lrow;
                    Ccat[(size_t)grow * NCAT + gcol] = f2bf(acc[m][n][v] + bias4[n]);
                }
            }
        }
    }
}

// ---- fused edge pass: one wave per target walks its CSR edge list.
// alpha = <Q[tgt,h], Ktil[src,t,h]> (scale/p_rel folded into Wcat), ex = exp(alpha),
// es += ex, acc[t] += ex*V[src,h]; epilogue: Acat[tgt*4+h][t*64+:] = acc[t]/(es+1e-16).
__global__ __launch_bounds__(256) void edge_fused(const unsigned short* __restrict__ Ccat,
                                                  const int* __restrict__ esrc,
                                                  const int* __restrict__ off,
                                                  const int* __restrict__ perm,
                                                  unsigned short* __restrict__ Acat) {
    const int wid = threadIdx.x >> 6, lane = threadIdx.x & 63;
    const int tgt = (blockIdx.x << 2) + wid;
    const int h = lane >> 4, f0 = (lane & 15) << 2;
    const int off0 = off[tgt];
    const int off1 = (tgt == N_NODES - 1) ? TE : off[tgt + 1];
    const ushort4 qu = *(const ushort4*)(Ccat + (size_t)tgt * NCAT + 1280 + (h << 6) + f0);
    const float qx = bf2f(qu.x), qy = bf2f(qu.y), qz = bf2f(qu.z), qw = bf2f(qu.w);
    float es = 0.f;
    float4 a0 = make_float4(0, 0, 0, 0), a1 = a0, a2 = a0, a3 = a0, a4 = a0;
    for (int i = off0; i < off1; ++i) {
        const int e = perm[i];
        const int t = e / EPT;      // wave-uniform (all lanes share e)
        const int src = esrc[e];
        const size_t rowb = (size_t)src * NCAT;
        const ushort4 ku = *(const ushort4*)(Ccat + rowb + ((t * 4 + h) << 6) + f0);
        const ushort4 vu = *(const ushort4*)(Ccat + rowb + 1536 + (h << 6) + f0);
        float part = qx * bf2f(ku.x) + qy * bf2f(ku.y) + qz * bf2f(ku.z) + qw * bf2f(ku.w);
        part += __shfl_xor(part, 1);
        part += __shfl_xor(part, 2);
        part += __shfl_xor(part, 4);
        part += __shfl_xor(part, 8);
        const float ex = __expf(part);
        es += ex;
        const float mx = ex * bf2f(vu.x), my = ex * bf2f(vu.y);
        const float mz = ex * bf2f(vu.z), mw = ex * bf2f(vu.w);
        if (t == 0)      { a0.x += mx; a0.y += my; a0.z += mz; a0.w += mw; }
        else if (t == 1) { a1.x += mx; a1.y += my; a1.z += mz; a1.w += mw; }
        else if (t == 2) { a2.x += mx; a2.y += my; a2.z += mz; a2.w += mw; }
        else if (t == 3) { a3.x += mx; a3.y += my; a3.z += mz; a3.w += mw; }
        else             { a4.x += mx; a4.y += my; a4.z += mz; a4.w += mw; }
    }
    const float inv = 1.f / (es + 1e-16f);
    const size_t r = (size_t)tgt * NHEAD + h;
    unsigned short* base = Acat + r * (NTYPES * HDIM) + f0;
    ushort4 u;
    u.x = f2bf(a0.x * inv); u.y = f2bf(a0.y * inv); u.z = f2bf(a0.z * inv); u.w = f2bf(a0.w * inv);
    *(ushort4*)(base + 0 * HDIM) = u;
    u.x = f2bf(a1.x * inv); u.y = f2bf(a1.y * inv); u.z = f2bf(a1.z * inv); u.w = f2bf(a1.w * inv);
    *(ushort4*)(base + 1 * HDIM) = u;
    u.x = f2bf(a2.x * inv); u.y = f2bf(a2.y * inv); u.z = f2bf(a2.z * inv); u.w = f2bf(a2.w * inv);
    *(ushort4*)(base + 2 * HDIM) = u;
    u.x = f2bf(a3.x * inv); u.y = f2bf(a3.y * inv); u.z = f2bf(a3.z * inv); u.w = f2bf(a3.w * inv);
    *(ushort4*)(base + 3 * HDIM) = u;
    u.x = f2bf(a4.x * inv); u.y = f2bf(a4.y * inv); u.z = f2bf(a4.z * inv); u.w = f2bf(a4.w * inv);
    *(ushort4*)(base + 4 * HDIM) = u;
}

// ---- MFMA epilogue GEMM: aggVb[120000,64](bf16) = gelu(Acat[120000,320] @ vrelT^T) ----
__global__ __launch_bounds__(256) void gemm_cat_mfma(const unsigned short* __restrict__ Acat,
                                                     const unsigned short* __restrict__ vrelT,
                                                     unsigned short* __restrict__ aggVb) {
    __shared__ unsigned short As[256 * 40];
    __shared__ unsigned short Bs[64 * 40];
    const int brow0 = blockIdx.x * 256;
    const int t = threadIdx.x;
    const int wid = t >> 6, lane = t & 63;
    const int lrow = lane & 15, kb = lane >> 4;
    const int r0 = t >> 2, q0 = (t & 3) * 8;

    f32x4 acc[4][4];
#pragma unroll
    for (int m = 0; m < 4; ++m)
#pragma unroll
        for (int n = 0; n < 4; ++n) acc[m][n] = (f32x4)0.f;

    for (int kt = 0; kt < 320; kt += 32) {
        uint4 a[4];
#pragma unroll
        for (int i = 0; i < 4; ++i) {
            const int row = min(brow0 + r0 + 64 * i, 120000 - 1);
            a[i] = *(const uint4*)(Acat + (size_t)row * 320 + kt + q0);
        }
        const uint4 b0 = *(const uint4*)(vrelT + (size_t)r0 * 320 + kt + q0);
        __syncthreads();
#pragma unroll
        for (int i = 0; i < 4; ++i)
            *(uint4*)&As[(r0 + 64 * i) * 40 + q0] = a[i];
        *(uint4*)&Bs[r0 * 40 + q0] = b0;
        __syncthreads();
        short8 af[4], bf_[4];
#pragma unroll
        for (int m = 0; m < 4; ++m)
            af[m] = *(const short8*)&As[(wid * 64 + m * 16 + lrow) * 40 + kb * 8];
#pragma unroll
        for (int n = 0; n < 4; ++n)
            bf_[n] = *(const short8*)&Bs[(n * 16 + lrow) * 40 + kb * 8];
#pragma unroll
        for (int m = 0; m < 4; ++m)
#pragma unroll
            for (int n = 0; n < 4; ++n)
                acc[m][n] = __builtin_amdgcn_mfma_f32_16x16x32_bf16(af[m], bf_[n], acc[m][n], 0, 0, 0);
    }

#pragma unroll
    for (int m = 0; m < 4; ++m) {
        const int gr0 = brow0 + wid * 64 + m * 16 + kb * 4;
#pragma unroll
        for (int v = 0; v < 4; ++v) {
            const int grow = gr0 + v;
            if (grow < 120000) {
#pragma unroll
                for (int n = 0; n < 4; ++n) {
                    const int gcol = n * 16 + lrow;
                    const float x = acc[m][n][v];
                    const float g = 0.5f * x * (1.f + erff(x * 0.7071067811865475f));
                    aggVb[(size_t)grow * 64 + gcol] = f2bf(g);
                }
            }
        }
    }
}

// ---- MFMA out GEMM: out[30000,256] = sa*(aggVb @ Wob^T + out_b) + sb*h ----
__global__ __launch_bounds__(256) void gemm_out_mfma(const unsigned short* __restrict__ A,
                                                     const unsigned short* __restrict__ Wob,
                                                     const float* __restrict__ bias,
                                                     float* __restrict__ C,
                                                     const float* __restrict__ hres,
                                                     const float* __restrict__ skip) {
    __shared__ unsigned short As[128 * 40];
    __shared__ unsigned short Bs[128 * 40];
    const int brow0 = blockIdx.x * 128;
    const int bcol0 = blockIdx.y * 128;
    const int t = threadIdx.x;
    const int wid = t >> 6, lane = t & 63;
    const int wr = wid >> 1, wc = wid & 1;
    const int lrow = lane & 15, kb = lane >> 4;
    const int r0 = t >> 2, q0 = t & 3;
    const int r1 = (t + 256) >> 2, q1 = t & 3;

    f32x4 acc[4][4];
#pragma unroll
    for (int m = 0; m < 4; ++m)
#pragma unroll
        for (int n = 0; n < 4; ++n) acc[m][n] = (f32x4)0.f;

    for (int kt = 0; kt < 256; kt += 32) {
        const int ar0 = min(brow0 + r0, N_NODES - 1);
        const int ar1 = min(brow0 + r1, N_NODES - 1);
        const uint4 a0 = *(const uint4*)(A + (size_t)ar0 * 256 + kt + q0 * 8);
        const uint4 a1 = *(const uint4*)(A + (size_t)ar1 * 256 + kt + q1 * 8);
        const uint4 b0 = *(const uint4*)(Wob + (size_t)(bcol0 + r0) * 256 + kt + q0 * 8);
        const uint4 b1 = *(const uint4*)(Wob + (size_t)(bcol0 + r1) * 256 + kt + q1 * 8);
        __syncthreads();
        *(uint4*)&As[r0 * 40 + q0 * 8] = a0;
        *(uint4*)&As[r1 * 40 + q1 * 8] = a1;
        *(uint4*)&Bs[r0 * 40 + q0 * 8] = b0;
        *(uint4*)&Bs[r1 * 40 + q1 * 8] = b1;
        __syncthreads();
        short8 af[4], bf_[4];
#pragma unroll
        for (int m = 0; m < 4; ++m)
            af[m] = *(const short8*)&As[(wr * 64 + m * 16 + lrow) * 40 + kb * 8];
#pragma unroll
        for (int n = 0; n < 4; ++n)
            bf_[n] = *(const short8*)&Bs[(wc * 64 + n * 16 + lrow) * 40 + kb * 8];
#pragma unroll
        for (int m = 0; m < 4; ++m)
#pragma unroll
            for (int n = 0; n < 4; ++n)
                acc[m][n] = __builtin_amdgcn_mfma_f32_16x16x32_bf16(af[m], bf_[n], acc[m][n], 0, 0, 0);
    }

    const float s = skip[0];
    const float sa = 1.f / (1.f + expf(-s));
    const float sb = 1.f - sa;
    float bias4[4];
#pragma unroll
    for (int n = 0; n < 4; ++n) bias4[n] = bias[bcol0 + wc * 64 + n * 16 + lrow];
#pragma unroll
    for (int m = 0; m < 4; ++m) {
        const int gr0 = brow0 + wr * 64 + m * 16 + kb * 4;
#pragma unroll
        for (int v = 0; v < 4; ++v) {
            const int grow = gr0 + v;
            if (grow < N_NODES) {
#pragma unroll
                for (int n = 0; n < 4; ++n) {
                    const int gcol = bcol0 + wc * 64 + n * 16 + lrow;
                    const float val = acc[m][n][v] + bias4[n];
                    C[(size_t)grow * 256 + gcol] = sa * val + sb * hres[(size_t)grow * 256 + gcol];
                }
            }
        }
    }
}

extern "C" void kernel_launch(void* const* d_in, const int* in_sizes, int n_in,
                              void* d_out, int out_size, void* d_ws, size_t ws_size,
                              hipStream_t stream) {
    const float* h      = (const float*)d_in[0];
    const int*   esrc   = (const int*)d_in[1];
    const int*   etgt   = (const int*)d_in[2];
    const float* kqv_w  = (const float*)d_in[3];
    const float* kqv_b  = (const float*)d_in[4];
    const float* out_w  = (const float*)d_in[5];
    const float* out_b  = (const float*)d_in[6];
    const float* k_rel  = (const float*)d_in[7];
    const float* v_rel  = (const float*)d_in[8];
    const float* skip   = (const float*)d_in[9];
    const float* p_rel  = (const float*)d_in[10];
    float* out = (float*)d_out;

    // workspace layout (float-sized slots):
    float* ws = (float*)d_ws;
    unsigned short* Ccat     = (unsigned short*)ws;                 // 53,760,000 ushorts = 26,880,000 slots [0 .. 26.88M)
    int*            deg      = (int*)(ws + 26880000);               //     30,000 -> 26,910,000
    int*            off      = (int*)(ws + 26910000);               //     30,000 -> 26,940,000
    int*            cursor   = (int*)(ws + 26940000);               //     30,000 -> 26,970,000
    int*            perm     = (int*)(ws + 26970000);               //    200,000 -> 27,170,000
    unsigned short* aggVb    = (unsigned short*)(ws + 27170000);    // 7,680,000 ushorts = 3,840,000 slots -> 31,010,000
    unsigned short* Acat     = (unsigned short*)(ws + 31010000);    // 38,400,000 ushorts = 19,200,000 slots -> 50,210,000
    // LATE-READ buffers (consumed AFTER Acat is written) -> past Acat's end:
    unsigned short* vrelT    = (unsigned short*)(ws + 50210000);    // 10,240 slots -> 50,220,240
    unsigned short* Wob      = (unsigned short*)(ws + 50220240);    // 32,768 slots -> 50,253,008
    // EARLY-DEAD aliases inside Acat's span (read only BEFORE edge_fused writes Acat):
    unsigned short* hb       = (unsigned short*)(ws + 41530000);    // 3,840,000 slots -> ends 45,370,000 (< 50.21M ok)
    unsigned short* Wcat     = (unsigned short*)(ws + 45370000);    // 229,376 slots -> ends 45,599,376
    float*          bias_cat = ws + 45600000;                       // 1,792 -> ends 45,601,792 (< 50.21M ok)
    // total footprint: 50,253,008 float slots = 201.0 MB

    hipLaunchKernelGGL(init_kernel, dim3(118), dim3(256), 0, stream, deg);
    hipLaunchKernelGGL(hist_kernel, dim3(782), dim3(256), 0, stream, etgt, deg);
    hipLaunchKernelGGL(scan_kernel, dim3(1), dim3(1024), 0, stream, deg, off, cursor);
    hipLaunchKernelGGL(scatter_kernel, dim3(782), dim3(256), 0, stream, etgt, cursor, perm);
    hipLaunchKernelGGL(weight_prep, dim3(NCAT), dim3(256), 0, stream,
                       kqv_w, kqv_b, k_rel, p_rel, Wcat, bias_cat);
    hipLaunchKernelGGL(h2bf_kernel, dim3(7500), dim3(256), 0, stream, h, hb);
    hipLaunchKernelGGL(vrelT_prep, dim3(64), dim3(320), 0, stream, v_rel, vrelT);
    hipLaunchKernelGGL(owb_prep, dim3(256), dim3(256), 0, stream, out_w, Wob);
    hipLaunchKernelGGL(mfma_gemm, dim3(235, 14), dim3(256), 0, stream,
                       hb, Wcat, bias_cat, Ccat);
    hipLaunchKernelGGL(edge_fused, dim3(N_NODES / 4), dim3(256), 0, stream,
                       Ccat, esrc, off, perm, Acat);
    hipLaunchKernelGGL(gemm_cat_mfma, dim3(469), dim3(256), 0, stream,
                       Acat, vrelT, aggVb);
    hipLaunchKernelGGL(gemm_out_mfma, dim3(235, 2), dim3(256), 0, stream,
                       aggVb, Wob, out_b, out, h, skip);
}

// Round 7
// 246.392 us; speedup vs baseline: 4.5296x; 1.0953x over previous
//
#include <hip/hip_runtime.h>
#include <hip/hip_bf16.h>
#include <math.h>

#define N_NODES 30000
#define NHEAD   4
#define HDIM    64
#define NTYPES  5
#define EPT     40000
#define TE      (NTYPES * EPT)
#define KDIM    256
#define NCAT    1792   // 1280 Ktil | 256 Q | 256 V

typedef __attribute__((ext_vector_type(8))) short short8;
typedef __attribute__((ext_vector_type(4))) float f32x4;

__device__ __forceinline__ unsigned short f2bf(float f) {
    __hip_bfloat16 h = __float2bfloat16(f);
    return *reinterpret_cast<unsigned short*>(&h);
}
__device__ __forceinline__ float bf2f(unsigned short u) {
    return __uint_as_float((unsigned)u << 16);
}

// async global->LDS, 16B per lane. LDS dest is wave-uniform base + lane*16 (linear).
__device__ __forceinline__ void gload16(const unsigned short* g, unsigned short* l) {
    __builtin_amdgcn_global_load_lds((const __attribute__((address_space(1))) void*)g,
                                     (__attribute__((address_space(3))) void*)l, 16, 0, 0);
}

// ---- init: zero deg ----
__global__ __launch_bounds__(256) void init_kernel(int* __restrict__ deg) {
    const int gid = blockIdx.x * blockDim.x + threadIdx.x;
    if (gid < N_NODES) deg[gid] = 0;
}

// ---- CSR build: histogram ----
__global__ __launch_bounds__(256) void hist_kernel(const int* __restrict__ etgt,
                                                   int* __restrict__ deg) {
    const int stride = gridDim.x * blockDim.x;
    for (int i = blockIdx.x * blockDim.x + threadIdx.x; i < TE; i += stride)
        atomicAdd(&deg[etgt[i]], 1);
}

// ---- CSR build: single-block exclusive scan over 30000 degrees ----
__global__ __launch_bounds__(1024) void scan_kernel(const int* __restrict__ deg,
                                                    int* __restrict__ off,
                                                    int* __restrict__ cursor) {
    __shared__ int sums[1024];
    const int t = threadIdx.x;
    int local[30];
    int s = 0;
    const int base = t * 30;
#pragma unroll
    for (int j = 0; j < 30; ++j) {
        const int idx = base + j;
        const int d = (idx < N_NODES) ? deg[idx] : 0;
        local[j] = d;
        s += d;
    }
    sums[t] = s;
    __syncthreads();
    for (int d = 1; d < 1024; d <<= 1) {
        const int v = (t >= d) ? sums[t - d] : 0;
        __syncthreads();
        sums[t] += v;
        __syncthreads();
    }
    int run = (t > 0) ? sums[t - 1] : 0;
#pragma unroll
    for (int j = 0; j < 30; ++j) {
        const int idx = base + j;
        if (idx < N_NODES) {
            off[idx] = run;
            cursor[idx] = run;
            run += local[j];
        }
    }
}

// ---- CSR build: scatter edge ids into per-target buckets ----
__global__ __launch_bounds__(256) void scatter_kernel(const int* __restrict__ etgt,
                                                      int* __restrict__ cursor,
                                                      int* __restrict__ perm) {
    const int stride = gridDim.x * blockDim.x;
    for (int e = blockIdx.x * blockDim.x + threadIdx.x; e < TE; e += stride) {
        const int pos = atomicAdd(&cursor[etgt[e]], 1);
        perm[pos] = e;
    }
}

// ---- weight prep: Wcat[1792,256] bf16 (+bias_cat f32) ----
__global__ __launch_bounds__(256) void weight_prep(const float* __restrict__ kqv_w,
                                                   const float* __restrict__ kqv_b,
                                                   const float* __restrict__ k_rel,
                                                   const float* __restrict__ p_rel,
                                                   unsigned short* __restrict__ Wcat,
                                                   float* __restrict__ bias_cat) {
    const int r = blockIdx.x;
    const int f = threadIdx.x;
    if (r < 1280) {
        const int t = r >> 8, h = (r >> 6) & 3, d = r & 63;
        const float sc = 0.125f * p_rel[t * NHEAD + h];
        float acc = 0.f;
#pragma unroll
        for (int fp = 0; fp < 64; ++fp)
            acc = fmaf(kqv_w[(size_t)(h * 64 + fp) * 256 + f], k_rel[t * 4096 + fp * 64 + d], acc);
        Wcat[(size_t)r * 256 + f] = f2bf(acc * sc);
        if (f == 0) {
            float b = 0.f;
#pragma unroll
            for (int fp = 0; fp < 64; ++fp)
                b = fmaf(kqv_b[h * 64 + fp], k_rel[t * 4096 + fp * 64 + d], b);
            bias_cat[r] = b * sc;
        }
    } else {
        const int src_row = r - 1024;  // 1280->256 (Q), 1536->512 (V)
        Wcat[(size_t)r * 256 + f] = f2bf(kqv_w[(size_t)src_row * 256 + f]);
        if (f == 0) bias_cat[r] = kqv_b[src_row];
    }
}

// ---- h -> bf16 ----
__global__ __launch_bounds__(256) void h2bf_kernel(const float* __restrict__ h,
                                                   unsigned short* __restrict__ hb) {
    const int i = blockIdx.x * 256 + threadIdx.x;
    if (i >= N_NODES * KDIM / 4) return;
    const float4 v = ((const float4*)h)[i];
    ushort4 u;
    u.x = f2bf(v.x); u.y = f2bf(v.y); u.z = f2bf(v.z); u.w = f2bf(v.w);
    ((ushort4*)hb)[i] = u;
}

// ---- v_rel[320,64] -> vrelT[64,320] bf16 ----
__global__ __launch_bounds__(320) void vrelT_prep(const float* __restrict__ v_rel,
                                                  unsigned short* __restrict__ vrelT) {
    const int f = blockIdx.x;        // 0..63 output row (col of v_rel)
    const int k = threadIdx.x;       // 0..319 = t*64+d
    vrelT[f * 320 + k] = f2bf(v_rel[(k >> 6) * 4096 + (k & 63) * 64 + f]);
}

// ---- out_w -> bf16 ----
__global__ __launch_bounds__(256) void owb_prep(const float* __restrict__ out_w,
                                                unsigned short* __restrict__ Wob) {
    const int i = blockIdx.x * 256 + threadIdx.x;
    Wob[i] = f2bf(out_w[i]);
}

// ---- MFMA GEMM: Ccat[30000,1792](bf16) = hb[30000,256] @ Wcat^T + bias_cat ----
// 128x128 tile, BK=32, 4 waves (2x2). 2-phase double-buffered global_load_lds
// staging (one barrier per K-step; next-tile DMA drains under current compute).
// 16B-chunk XOR swizzle on global source + ds_read address (proven round 6).
// XCD-chunked bijective blockIdx swizzle: each XCD owns contiguous row-panels,
// col-tiles fastest -> A-panel fetched once per XCD L2.
__global__ __launch_bounds__(256) void mfma_gemm(const unsigned short* __restrict__ hb,
                                                 const unsigned short* __restrict__ Wcat,
                                                 const float* __restrict__ bias_cat,
                                                 unsigned short* __restrict__ Ccat) {
    __shared__ unsigned short As[2][128 * 32];
    __shared__ unsigned short Bs[2][128 * 32];
    // bijective chunked swizzle over 3290 = 235*14 blocks, 8 XCDs (m204)
    const int orig = blockIdx.x;
    const int xcd = orig & 7, pos = orig >> 3;
    const int q = 3290 / 8, r = 3290 % 8;  // 411, 2
    const int wgid = (xcd < r ? xcd * (q + 1) : r * (q + 1) + (xcd - r) * q) + pos;
    const int brow0 = (wgid / 14) * 128;
    const int bcol0 = (wgid % 14) * 128;

    const int t = threadIdx.x;
    const int wid = t >> 6, lane = t & 63;
    const int wr = wid >> 1, wc = wid & 1;
    const int lrow = lane & 15, kb = lane >> 4;
    // staging: lane l fills LDS chunk (row l>>2, chunk l&3) <- global chunk (l&3)^((l>>3)&3)
    const int srow = lane >> 2;
    const int schunk = ((lane & 3) ^ ((lane >> 3) & 3)) * 8;   // ushort offset in row
    const int rchunk = (kb ^ ((lrow >> 1) & 3)) * 8;           // swizzled read chunk

    const int arow0 = min(brow0 + wid * 16 + srow, N_NODES - 1);
    const int arow1 = min(brow0 + 64 + wid * 16 + srow, N_NODES - 1);
    const int brw0 = bcol0 + wid * 16 + srow;        // always < 1792
    const int brw1 = bcol0 + 64 + wid * 16 + srow;

    auto stage = [&](int buf, int kt) {
        gload16(hb + (size_t)arow0 * KDIM + kt + schunk, &As[buf][wid * 512]);
        gload16(hb + (size_t)arow1 * KDIM + kt + schunk, &As[buf][2048 + wid * 512]);
        gload16(Wcat + (size_t)brw0 * KDIM + kt + schunk, &Bs[buf][wid * 512]);
        gload16(Wcat + (size_t)brw1 * KDIM + kt + schunk, &Bs[buf][2048 + wid * 512]);
    };

    f32x4 acc[4][4];
#pragma unroll
    for (int m = 0; m < 4; ++m)
#pragma unroll
        for (int n = 0; n < 4; ++n) acc[m][n] = (f32x4)0.f;

    stage(0, 0);
    __syncthreads();   // drain prologue DMA (vmcnt(0) before s_barrier)
    int cur = 0;
    for (int kt = 0; kt < KDIM; kt += 32) {
        if (kt + 32 < KDIM) stage(cur ^ 1, kt + 32);   // issue next-tile DMA first
        short8 af[4], bfr[4];
#pragma unroll
        for (int m = 0; m < 4; ++m)
            af[m] = *(const short8*)&As[cur][(wr * 64 + m * 16 + lrow) * 32 + rchunk];
#pragma unroll
        for (int n = 0; n < 4; ++n)
            bfr[n] = *(const short8*)&Bs[cur][(wc * 64 + n * 16 + lrow) * 32 + rchunk];
#pragma unroll
        for (int m = 0; m < 4; ++m)
#pragma unroll
            for (int n = 0; n < 4; ++n)
                acc[m][n] = __builtin_amdgcn_mfma_f32_16x16x32_bf16(af[m], bfr[n], acc[m][n], 0, 0, 0);
        __syncthreads();   // one barrier/step: drains next-tile DMA + fences reads
        cur ^= 1;
    }

    float bias4[4];
#pragma unroll
    for (int n = 0; n < 4; ++n) bias4[n] = bias_cat[bcol0 + wc * 64 + n * 16 + lrow];
#pragma unroll
    for (int m = 0; m < 4; ++m) {
        const int gr0 = brow0 + wr * 64 + m * 16 + kb * 4;
#pragma unroll
        for (int v = 0; v < 4; ++v) {
            const int grow = gr0 + v;
            if (grow < N_NODES) {
#pragma unroll
                for (int n = 0; n < 4; ++n) {
                    const int gcol = bcol0 + wc * 64 + n * 16 + lrow;
                    Ccat[(size_t)grow * NCAT + gcol] = f2bf(acc[m][n][v] + bias4[n]);
                }
            }
        }
    }
}

// ---- fused edge pass: one wave per target walks its CSR edge list (unroll-2).
// alpha = <Q[tgt,h], Ktil[src,t,h]>, ex = exp(alpha), es += ex, acc[t] += ex*V[src,h];
// epilogue: Acat[tgt*4+h][t*64+:] = acc[t]/(es+1e-16).
__global__ __launch_bounds__(256) void edge_fused(const unsigned short* __restrict__ Ccat,
                                                  const int* __restrict__ esrc,
                                                  const int* __restrict__ off,
                                                  const int* __restrict__ perm,
                                                  unsigned short* __restrict__ Acat) {
    const int wid = threadIdx.x >> 6, lane = threadIdx.x & 63;
    const int tgt = (blockIdx.x << 2) + wid;
    const int h = lane >> 4, f0 = (lane & 15) << 2;
    const int off0 = off[tgt];
    const int off1 = (tgt == N_NODES - 1) ? TE : off[tgt + 1];
    const ushort4 qu = *(const ushort4*)(Ccat + (size_t)tgt * NCAT + 1280 + (h << 6) + f0);
    const float qx = bf2f(qu.x), qy = bf2f(qu.y), qz = bf2f(qu.z), qw = bf2f(qu.w);
    const int voff = 1536 + (h << 6) + f0;
    float es = 0.f;
    float4 a0 = make_float4(0, 0, 0, 0), a1 = a0, a2 = a0, a3 = a0, a4 = a0;
    int i = off0;
    while (i < off1) {
        const bool two = (i + 1 < off1);
        const int e0 = perm[i];
        const int e1 = two ? perm[i + 1] : e0;
        const int t0 = e0 / EPT, t1 = e1 / EPT;       // wave-uniform
        const int s0 = esrc[e0], s1 = esrc[e1];
        const size_t rb0 = (size_t)s0 * NCAT, rb1 = (size_t)s1 * NCAT;
        // issue all 4 gathers before any compute (2x memory-level parallelism)
        const ushort4 ku0 = *(const ushort4*)(Ccat + rb0 + ((t0 * 4 + h) << 6) + f0);
        const ushort4 vu0 = *(const ushort4*)(Ccat + rb0 + voff);
        const ushort4 ku1 = *(const ushort4*)(Ccat + rb1 + ((t1 * 4 + h) << 6) + f0);
        const ushort4 vu1 = *(const ushort4*)(Ccat + rb1 + voff);
        float p0 = qx * bf2f(ku0.x) + qy * bf2f(ku0.y) + qz * bf2f(ku0.z) + qw * bf2f(ku0.w);
        float p1 = qx * bf2f(ku1.x) + qy * bf2f(ku1.y) + qz * bf2f(ku1.z) + qw * bf2f(ku1.w);
        p0 += __shfl_xor(p0, 1); p1 += __shfl_xor(p1, 1);
        p0 += __shfl_xor(p0, 2); p1 += __shfl_xor(p1, 2);
        p0 += __shfl_xor(p0, 4); p1 += __shfl_xor(p1, 4);
        p0 += __shfl_xor(p0, 8); p1 += __shfl_xor(p1, 8);
        {
            const float ex = __expf(p0);
            es += ex;
            const float mx = ex * bf2f(vu0.x), my = ex * bf2f(vu0.y);
            const float mz = ex * bf2f(vu0.z), mw = ex * bf2f(vu0.w);
            if (t0 == 0)      { a0.x += mx; a0.y += my; a0.z += mz; a0.w += mw; }
            else if (t0 == 1) { a1.x += mx; a1.y += my; a1.z += mz; a1.w += mw; }
            else if (t0 == 2) { a2.x += mx; a2.y += my; a2.z += mz; a2.w += mw; }
            else if (t0 == 3) { a3.x += mx; a3.y += my; a3.z += mz; a3.w += mw; }
            else              { a4.x += mx; a4.y += my; a4.z += mz; a4.w += mw; }
        }
        if (two) {
            const float ex = __expf(p1);
            es += ex;
            const float mx = ex * bf2f(vu1.x), my = ex * bf2f(vu1.y);
            const float mz = ex * bf2f(vu1.z), mw = ex * bf2f(vu1.w);
            if (t1 == 0)      { a0.x += mx; a0.y += my; a0.z += mz; a0.w += mw; }
            else if (t1 == 1) { a1.x += mx; a1.y += my; a1.z += mz; a1.w += mw; }
            else if (t1 == 2) { a2.x += mx; a2.y += my; a2.z += mz; a2.w += mw; }
            else if (t1 == 3) { a3.x += mx; a3.y += my; a3.z += mz; a3.w += mw; }
            else              { a4.x += mx; a4.y += my; a4.z += mz; a4.w += mw; }
        }
        i += two ? 2 : 1;
    }
    const float inv = 1.f / (es + 1e-16f);
    const size_t rr = (size_t)tgt * NHEAD + h;
    unsigned short* base = Acat + rr * (NTYPES * HDIM) + f0;
    ushort4 u;
    u.x = f2bf(a0.x * inv); u.y = f2bf(a0.y * inv); u.z = f2bf(a0.z * inv); u.w = f2bf(a0.w * inv);
    *(ushort4*)(base + 0 * HDIM) = u;
    u.x = f2bf(a1.x * inv); u.y = f2bf(a1.y * inv); u.z = f2bf(a1.z * inv); u.w = f2bf(a1.w * inv);
    *(ushort4*)(base + 1 * HDIM) = u;
    u.x = f2bf(a2.x * inv); u.y = f2bf(a2.y * inv); u.z = f2bf(a2.z * inv); u.w = f2bf(a2.w * inv);
    *(ushort4*)(base + 2 * HDIM) = u;
    u.x = f2bf(a3.x * inv); u.y = f2bf(a3.y * inv); u.z = f2bf(a3.z * inv); u.w = f2bf(a3.w * inv);
    *(ushort4*)(base + 3 * HDIM) = u;
    u.x = f2bf(a4.x * inv); u.y = f2bf(a4.y * inv); u.z = f2bf(a4.z * inv); u.w = f2bf(a4.w * inv);
    *(ushort4*)(base + 4 * HDIM) = u;
}

// ---- MFMA epilogue GEMM: aggVb[120000,64](bf16) = gelu(Acat[120000,320] @ vrelT^T) ----
__global__ __launch_bounds__(256) void gemm_cat_mfma(const unsigned short* __restrict__ Acat,
                                                     const unsigned short* __restrict__ vrelT,
                                                     unsigned short* __restrict__ aggVb) {
    __shared__ unsigned short As[256 * 40];
    __shared__ unsigned short Bs[64 * 40];
    const int brow0 = blockIdx.x * 256;
    const int t = threadIdx.x;
    const int wid = t >> 6, lane = t & 63;
    const int lrow = lane & 15, kb = lane >> 4;
    const int r0 = t >> 2, q0 = (t & 3) * 8;

    f32x4 acc[4][4];
#pragma unroll
    for (int m = 0; m < 4; ++m)
#pragma unroll
        for (int n = 0; n < 4; ++n) acc[m][n] = (f32x4)0.f;

    for (int kt = 0; kt < 320; kt += 32) {
        uint4 a[4];
#pragma unroll
        for (int i = 0; i < 4; ++i) {
            const int row = min(brow0 + r0 + 64 * i, 120000 - 1);
            a[i] = *(const uint4*)(Acat + (size_t)row * 320 + kt + q0);
        }
        const uint4 b0 = *(const uint4*)(vrelT + (size_t)r0 * 320 + kt + q0);
        __syncthreads();
#pragma unroll
        for (int i = 0; i < 4; ++i)
            *(uint4*)&As[(r0 + 64 * i) * 40 + q0] = a[i];
        *(uint4*)&Bs[r0 * 40 + q0] = b0;
        __syncthreads();
        short8 af[4], bf_[4];
#pragma unroll
        for (int m = 0; m < 4; ++m)
            af[m] = *(const short8*)&As[(wid * 64 + m * 16 + lrow) * 40 + kb * 8];
#pragma unroll
        for (int n = 0; n < 4; ++n)
            bf_[n] = *(const short8*)&Bs[(n * 16 + lrow) * 40 + kb * 8];
#pragma unroll
        for (int m = 0; m < 4; ++m)
#pragma unroll
            for (int n = 0; n < 4; ++n)
                acc[m][n] = __builtin_amdgcn_mfma_f32_16x16x32_bf16(af[m], bf_[n], acc[m][n], 0, 0, 0);
    }

#pragma unroll
    for (int m = 0; m < 4; ++m) {
        const int gr0 = brow0 + wid * 64 + m * 16 + kb * 4;
#pragma unroll
        for (int v = 0; v < 4; ++v) {
            const int grow = gr0 + v;
            if (grow < 120000) {
#pragma unroll
                for (int n = 0; n < 4; ++n) {
                    const int gcol = n * 16 + lrow;
                    const float x = acc[m][n][v];
                    const float g = 0.5f * x * (1.f + erff(x * 0.7071067811865475f));
                    aggVb[(size_t)grow * 64 + gcol] = f2bf(g);
                }
            }
        }
    }
}

// ---- MFMA out GEMM: out[30000,256] = sa*(aggVb @ Wob^T + out_b) + sb*h ----
__global__ __launch_bounds__(256) void gemm_out_mfma(const unsigned short* __restrict__ A,
                                                     const unsigned short* __restrict__ Wob,
                                                     const float* __restrict__ bias,
                                                     float* __restrict__ C,
                                                     const float* __restrict__ hres,
                                                     const float* __restrict__ skip) {
    __shared__ unsigned short As[128 * 40];
    __shared__ unsigned short Bs[128 * 40];
    const int brow0 = blockIdx.x * 128;
    const int bcol0 = blockIdx.y * 128;
    const int t = threadIdx.x;
    const int wid = t >> 6, lane = t & 63;
    const int wr = wid >> 1, wc = wid & 1;
    const int lrow = lane & 15, kb = lane >> 4;
    const int r0 = t >> 2, q0 = t & 3;
    const int r1 = (t + 256) >> 2, q1 = t & 3;

    f32x4 acc[4][4];
#pragma unroll
    for (int m = 0; m < 4; ++m)
#pragma unroll
        for (int n = 0; n < 4; ++n) acc[m][n] = (f32x4)0.f;

    for (int kt = 0; kt < 256; kt += 32) {
        const int ar0 = min(brow0 + r0, N_NODES - 1);
        const int ar1 = min(brow0 + r1, N_NODES - 1);
        const uint4 a0 = *(const uint4*)(A + (size_t)ar0 * 256 + kt + q0 * 8);
        const uint4 a1 = *(const uint4*)(A + (size_t)ar1 * 256 + kt + q1 * 8);
        const uint4 b0 = *(const uint4*)(Wob + (size_t)(bcol0 + r0) * 256 + kt + q0 * 8);
        const uint4 b1 = *(const uint4*)(Wob + (size_t)(bcol0 + r1) * 256 + kt + q1 * 8);
        __syncthreads();
        *(uint4*)&As[r0 * 40 + q0 * 8] = a0;
        *(uint4*)&As[r1 * 40 + q1 * 8] = a1;
        *(uint4*)&Bs[r0 * 40 + q0 * 8] = b0;
        *(uint4*)&Bs[r1 * 40 + q1 * 8] = b1;
        __syncthreads();
        short8 af[4], bf_[4];
#pragma unroll
        for (int m = 0; m < 4; ++m)
            af[m] = *(const short8*)&As[(wr * 64 + m * 16 + lrow) * 40 + kb * 8];
#pragma unroll
        for (int n = 0; n < 4; ++n)
            bf_[n] = *(const short8*)&Bs[(wc * 64 + n * 16 + lrow) * 40 + kb * 8];
#pragma unroll
        for (int m = 0; m < 4; ++m)
#pragma unroll
            for (int n = 0; n < 4; ++n)
                acc[m][n] = __builtin_amdgcn_mfma_f32_16x16x32_bf16(af[m], bf_[n], acc[m][n], 0, 0, 0);
    }

    const float s = skip[0];
    const float sa = 1.f / (1.f + expf(-s));
    const float sb = 1.f - sa;
    float bias4[4];
#pragma unroll
    for (int n = 0; n < 4; ++n) bias4[n] = bias[bcol0 + wc * 64 + n * 16 + lrow];
#pragma unroll
    for (int m = 0; m < 4; ++m) {
        const int gr0 = brow0 + wr * 64 + m * 16 + kb * 4;
#pragma unroll
        for (int v = 0; v < 4; ++v) {
            const int grow = gr0 + v;
            if (grow < N_NODES) {
#pragma unroll
                for (int n = 0; n < 4; ++n) {
                    const int gcol = bcol0 + wc * 64 + n * 16 + lrow;
                    const float val = acc[m][n][v] + bias4[n];
                    C[(size_t)grow * 256 + gcol] = sa * val + sb * hres[(size_t)grow * 256 + gcol];
                }
            }
        }
    }
}

extern "C" void kernel_launch(void* const* d_in, const int* in_sizes, int n_in,
                              void* d_out, int out_size, void* d_ws, size_t ws_size,
                              hipStream_t stream) {
    const float* h      = (const float*)d_in[0];
    const int*   esrc   = (const int*)d_in[1];
    const int*   etgt   = (const int*)d_in[2];
    const float* kqv_w  = (const float*)d_in[3];
    const float* kqv_b  = (const float*)d_in[4];
    const float* out_w  = (const float*)d_in[5];
    const float* out_b  = (const float*)d_in[6];
    const float* k_rel  = (const float*)d_in[7];
    const float* v_rel  = (const float*)d_in[8];
    const float* skip   = (const float*)d_in[9];
    const float* p_rel  = (const float*)d_in[10];
    float* out = (float*)d_out;

    // workspace layout (float-sized slots):
    float* ws = (float*)d_ws;
    unsigned short* Ccat     = (unsigned short*)ws;                 // 53,760,000 ushorts = 26,880,000 slots [0 .. 26.88M)
    int*            deg      = (int*)(ws + 26880000);               //     30,000 -> 26,910,000
    int*            off      = (int*)(ws + 26910000);               //     30,000 -> 26,940,000
    int*            cursor   = (int*)(ws + 26940000);               //     30,000 -> 26,970,000
    int*            perm     = (int*)(ws + 26970000);               //    200,000 -> 27,170,000
    unsigned short* aggVb    = (unsigned short*)(ws + 27170000);    // 3,840,000 slots -> 31,010,000
    unsigned short* Acat     = (unsigned short*)(ws + 31010000);    // 19,200,000 slots -> 50,210,000
    // LATE-READ buffers (consumed AFTER Acat is written) -> past Acat's end:
    unsigned short* vrelT    = (unsigned short*)(ws + 50210000);    // 10,240 slots -> 50,220,240
    unsigned short* Wob      = (unsigned short*)(ws + 50220240);    // 32,768 slots -> 50,253,008
    // EARLY-DEAD aliases inside Acat's span (read only BEFORE edge_fused writes Acat):
    unsigned short* hb       = (unsigned short*)(ws + 41530000);    // 3,840,000 slots -> ends 45,370,000 (< 50.21M ok)
    unsigned short* Wcat     = (unsigned short*)(ws + 45370000);    // 229,376 slots -> ends 45,599,376
    float*          bias_cat = ws + 45600000;                       // 1,792 -> ends 45,601,792 (< 50.21M ok)
    // total footprint: 50,253,008 float slots = 201.0 MB

    hipLaunchKernelGGL(init_kernel, dim3(118), dim3(256), 0, stream, deg);
    hipLaunchKernelGGL(hist_kernel, dim3(782), dim3(256), 0, stream, etgt, deg);
    hipLaunchKernelGGL(scan_kernel, dim3(1), dim3(1024), 0, stream, deg, off, cursor);
    hipLaunchKernelGGL(scatter_kernel, dim3(782), dim3(256), 0, stream, etgt, cursor, perm);
    hipLaunchKernelGGL(weight_prep, dim3(NCAT), dim3(256), 0, stream,
                       kqv_w, kqv_b, k_rel, p_rel, Wcat, bias_cat);
    hipLaunchKernelGGL(h2bf_kernel, dim3(7500), dim3(256), 0, stream, h, hb);
    hipLaunchKernelGGL(vrelT_prep, dim3(64), dim3(320), 0, stream, v_rel, vrelT);
    hipLaunchKernelGGL(owb_prep, dim3(256), dim3(256), 0, stream, out_w, Wob);
    hipLaunchKernelGGL(mfma_gemm, dim3(3290), dim3(256), 0, stream,
                       hb, Wcat, bias_cat, Ccat);
    hipLaunchKernelGGL(edge_fused, dim3(N_NODES / 4), dim3(256), 0, stream,
                       Ccat, esrc, off, perm, Acat);
    hipLaunchKernelGGL(gemm_cat_mfma, dim3(469), dim3(256), 0, stream,
                       Acat, vrelT, aggVb);
    hipLaunchKernelGGL(gemm_out_mfma, dim3(235, 2), dim3(256), 0, stream,
                       aggVb, Wob, out_b, out, h, skip);
}

// Round 8
// 236.914 us; speedup vs baseline: 4.7109x; 1.0400x over previous
//
#include <hip/hip_runtime.h>
#include <hip/hip_bf16.h>
#include <math.h>

#define N_NODES 30000
#define NHEAD   4
#define HDIM    64
#define NTYPES  5
#define EPT     40000
#define TE      (NTYPES * EPT)
#define KDIM    256
#define NCAT    1792   // 1280 Ktil | 256 Q | 256 V

typedef __attribute__((ext_vector_type(8))) short short8;
typedef __attribute__((ext_vector_type(4))) float f32x4;

__device__ __forceinline__ unsigned short f2bf(float f) {
    __hip_bfloat16 h = __float2bfloat16(f);
    return *reinterpret_cast<unsigned short*>(&h);
}
__device__ __forceinline__ float bf2f(unsigned short u) {
    return __uint_as_float((unsigned)u << 16);
}

// async global->LDS, 16B per lane. LDS dest is wave-uniform base + lane*16 (linear).
__device__ __forceinline__ void gload16(const unsigned short* g, unsigned short* l) {
    __builtin_amdgcn_global_load_lds((const __attribute__((address_space(1))) void*)g,
                                     (__attribute__((address_space(3))) void*)l, 16, 0, 0);
}

// ---- init: zero deg ----
__global__ __launch_bounds__(256) void init_kernel(int* __restrict__ deg) {
    const int gid = blockIdx.x * blockDim.x + threadIdx.x;
    if (gid < N_NODES) deg[gid] = 0;
}

// ---- CSR build: histogram ----
__global__ __launch_bounds__(256) void hist_kernel(const int* __restrict__ etgt,
                                                   int* __restrict__ deg) {
    const int stride = gridDim.x * blockDim.x;
    for (int i = blockIdx.x * blockDim.x + threadIdx.x; i < TE; i += stride)
        atomicAdd(&deg[etgt[i]], 1);
}

// ---- CSR build: single-block exclusive scan over 30000 degrees ----
__global__ __launch_bounds__(1024) void scan_kernel(const int* __restrict__ deg,
                                                    int* __restrict__ off,
                                                    int* __restrict__ cursor) {
    __shared__ int sums[1024];
    const int t = threadIdx.x;
    int local[30];
    int s = 0;
    const int base = t * 30;
#pragma unroll
    for (int j = 0; j < 30; ++j) {
        const int idx = base + j;
        const int d = (idx < N_NODES) ? deg[idx] : 0;
        local[j] = d;
        s += d;
    }
    sums[t] = s;
    __syncthreads();
    for (int d = 1; d < 1024; d <<= 1) {
        const int v = (t >= d) ? sums[t - d] : 0;
        __syncthreads();
        sums[t] += v;
        __syncthreads();
    }
    int run = (t > 0) ? sums[t - 1] : 0;
#pragma unroll
    for (int j = 0; j < 30; ++j) {
        const int idx = base + j;
        if (idx < N_NODES) {
            off[idx] = run;
            cursor[idx] = run;
            run += local[j];
        }
    }
}

// ---- CSR build: scatter edge ids into per-target buckets ----
__global__ __launch_bounds__(256) void scatter_kernel(const int* __restrict__ etgt,
                                                      int* __restrict__ cursor,
                                                      int* __restrict__ perm) {
    const int stride = gridDim.x * blockDim.x;
    for (int e = blockIdx.x * blockDim.x + threadIdx.x; e < TE; e += stride) {
        const int pos = atomicAdd(&cursor[etgt[e]], 1);
        perm[pos] = e;
    }
}

// ---- merged prep: [0,1792) weight_prep | [1792,9292) h2bf | [9292,9372) vrelT | [9372,9628) owb ----
__global__ __launch_bounds__(256) void prep_all(const float* __restrict__ kqv_w,
                                                const float* __restrict__ kqv_b,
                                                const float* __restrict__ k_rel,
                                                const float* __restrict__ p_rel,
                                                const float* __restrict__ h,
                                                const float* __restrict__ v_rel,
                                                const float* __restrict__ out_w,
                                                unsigned short* __restrict__ Wcat,
                                                float* __restrict__ bias_cat,
                                                unsigned short* __restrict__ hb,
                                                unsigned short* __restrict__ vrelT,
                                                unsigned short* __restrict__ Wob) {
    const int bid = blockIdx.x;
    const int tid = threadIdx.x;
    if (bid < 1792) {
        const int r = bid, f = tid;
        if (r < 1280) {
            const int t = r >> 8, hh = (r >> 6) & 3, d = r & 63;
            const float sc = 0.125f * p_rel[t * NHEAD + hh];
            float acc = 0.f;
#pragma unroll
            for (int fp = 0; fp < 64; ++fp)
                acc = fmaf(kqv_w[(size_t)(hh * 64 + fp) * 256 + f], k_rel[t * 4096 + fp * 64 + d], acc);
            Wcat[(size_t)r * 256 + f] = f2bf(acc * sc);
            if (f == 0) {
                float b = 0.f;
#pragma unroll
                for (int fp = 0; fp < 64; ++fp)
                    b = fmaf(kqv_b[hh * 64 + fp], k_rel[t * 4096 + fp * 64 + d], b);
                bias_cat[r] = b * sc;
            }
        } else {
            const int src_row = r - 1024;  // 1280->256 (Q), 1536->512 (V)
            Wcat[(size_t)r * 256 + f] = f2bf(kqv_w[(size_t)src_row * 256 + f]);
            if (f == 0) bias_cat[r] = kqv_b[src_row];
        }
    } else if (bid < 9292) {
        const int i = (bid - 1792) * 256 + tid;   // exactly 1,920,000 float4s
        const float4 v = ((const float4*)h)[i];
        ushort4 u;
        u.x = f2bf(v.x); u.y = f2bf(v.y); u.z = f2bf(v.z); u.w = f2bf(v.w);
        ((ushort4*)hb)[i] = u;
    } else if (bid < 9372) {
        const int idx = (bid - 9292) * 256 + tid;
        if (idx < 64 * 320) {
            const int f = idx / 320, k = idx - f * 320;
            vrelT[f * 320 + k] = f2bf(v_rel[(k >> 6) * 4096 + (k & 63) * 64 + f]);
        }
    } else {
        const int i = (bid - 9372) * 256 + tid;   // exactly 65,536
        Wob[i] = f2bf(out_w[i]);
    }
}

// ---- MFMA GEMM: Ccat[30000,1792](bf16) = hb[30000,256] @ Wcat^T + bias_cat ----
// 128x128 tile, BK=32, 4 waves (2x2). 2-phase double-buffered global_load_lds,
// 16B-chunk XOR swizzle (round 6), XCD-chunked bijective block swizzle (round 7).
// NEW: LDS-transpose epilogue -> dwordx4 C-stores (replaces 64 scalar 2B stores).
__global__ __launch_bounds__(256) void mfma_gemm(const unsigned short* __restrict__ hb,
                                                 const unsigned short* __restrict__ Wcat,
                                                 const float* __restrict__ bias_cat,
                                                 unsigned short* __restrict__ Ccat) {
    __shared__ unsigned short As[2][128 * 32];
    __shared__ unsigned short Bs[2][128 * 32];
    // bijective chunked swizzle over 3290 = 235*14 blocks, 8 XCDs (m204)
    const int orig = blockIdx.x;
    const int xcd = orig & 7, pos = orig >> 3;
    const int q = 3290 / 8, r = 3290 % 8;  // 411, 2
    const int wgid = (xcd < r ? xcd * (q + 1) : r * (q + 1) + (xcd - r) * q) + pos;
    const int brow0 = (wgid / 14) * 128;
    const int bcol0 = (wgid % 14) * 128;

    const int t = threadIdx.x;
    const int wid = t >> 6, lane = t & 63;
    const int wr = wid >> 1, wc = wid & 1;
    const int lrow = lane & 15, kb = lane >> 4;
    const int srow = lane >> 2;
    const int schunk = ((lane & 3) ^ ((lane >> 3) & 3)) * 8;   // staged (swizzled) chunk
    const int rchunk = (kb ^ ((lrow >> 1) & 3)) * 8;           // swizzled read chunk

    const int arow0 = min(brow0 + wid * 16 + srow, N_NODES - 1);
    const int arow1 = min(brow0 + 64 + wid * 16 + srow, N_NODES - 1);
    const int brw0 = bcol0 + wid * 16 + srow;        // always < 1792
    const int brw1 = bcol0 + 64 + wid * 16 + srow;

    auto stage = [&](int buf, int kt) {
        gload16(hb + (size_t)arow0 * KDIM + kt + schunk, &As[buf][wid * 512]);
        gload16(hb + (size_t)arow1 * KDIM + kt + schunk, &As[buf][2048 + wid * 512]);
        gload16(Wcat + (size_t)brw0 * KDIM + kt + schunk, &Bs[buf][wid * 512]);
        gload16(Wcat + (size_t)brw1 * KDIM + kt + schunk, &Bs[buf][2048 + wid * 512]);
    };

    f32x4 acc[4][4];
#pragma unroll
    for (int m = 0; m < 4; ++m)
#pragma unroll
        for (int n = 0; n < 4; ++n) acc[m][n] = (f32x4)0.f;

    stage(0, 0);
    __syncthreads();
    int cur = 0;
    for (int kt = 0; kt < KDIM; kt += 32) {
        if (kt + 32 < KDIM) stage(cur ^ 1, kt + 32);
        short8 af[4], bfr[4];
#pragma unroll
        for (int m = 0; m < 4; ++m)
            af[m] = *(const short8*)&As[cur][(wr * 64 + m * 16 + lrow) * 32 + rchunk];
#pragma unroll
        for (int n = 0; n < 4; ++n)
            bfr[n] = *(const short8*)&Bs[cur][(wc * 64 + n * 16 + lrow) * 32 + rchunk];
#pragma unroll
        for (int m = 0; m < 4; ++m)
#pragma unroll
            for (int n = 0; n < 4; ++n)
                acc[m][n] = __builtin_amdgcn_mfma_f32_16x16x32_bf16(af[m], bfr[n], acc[m][n], 0, 0, 0);
        __syncthreads();
        cur ^= 1;
    }

    // ---- LDS-transpose epilogue ----
    // Ts = 32x132 ushort tile (stride 132: kb-groups 8 banks apart on write,
    // 8B-aligned b64 reads). Reuses the dead As double-buffer (8192 >= 4224).
    unsigned short* Ts = &As[0][0];
    float bias4[4];
#pragma unroll
    for (int n = 0; n < 4; ++n) bias4[n] = bias_cat[bcol0 + wc * 64 + n * 16 + lrow];
    const int lrw = wr * 16 + kb * 4;       // + v  (local row in 32-row panel)
    const int lcw = wc * 64 + lrow;         // + n*16
#pragma unroll
    for (int m = 0; m < 4; ++m) {
        __syncthreads();   // prev m's reads (or K-loop) done before overwriting Ts
#pragma unroll
        for (int n = 0; n < 4; ++n)
#pragma unroll
            for (int v = 0; v < 4; ++v)
                Ts[(lrw + v) * 132 + lcw + n * 16] = f2bf(acc[m][n][v] + bias4[n]);
        __syncthreads();
#pragma unroll
        for (int rd = 0; rd < 2; ++rd) {
            const int lr = (t >> 4) + rd * 16;          // 0..31
            const int c0 = (t & 15) * 8;                // 0..120 step 8
            const int grow = brow0 + (lr >> 4) * 64 + m * 16 + (lr & 15);
            if (grow < N_NODES) {
                const uint2 lo = *(const uint2*)&Ts[lr * 132 + c0];
                const uint2 hi = *(const uint2*)&Ts[lr * 132 + c0 + 4];
                const uint4 o = make_uint4(lo.x, lo.y, hi.x, hi.y);
                *(uint4*)&Ccat[(size_t)grow * NCAT + bcol0 + c0] = o;
            }
        }
    }
}

// ---- fused edge pass: one wave per target walks its CSR edge list (unroll-2). ----
__global__ __launch_bounds__(256) void edge_fused(const unsigned short* __restrict__ Ccat,
                                                  const int* __restrict__ esrc,
                                                  const int* __restrict__ off,
                                                  const int* __restrict__ perm,
                                                  unsigned short* __restrict__ Acat) {
    const int wid = threadIdx.x >> 6, lane = threadIdx.x & 63;
    const int tgt = (blockIdx.x << 2) + wid;
    const int h = lane >> 4, f0 = (lane & 15) << 2;
    const int off0 = off[tgt];
    const int off1 = (tgt == N_NODES - 1) ? TE : off[tgt + 1];
    const ushort4 qu = *(const ushort4*)(Ccat + (size_t)tgt * NCAT + 1280 + (h << 6) + f0);
    const float qx = bf2f(qu.x), qy = bf2f(qu.y), qz = bf2f(qu.z), qw = bf2f(qu.w);
    const int voff = 1536 + (h << 6) + f0;
    float es = 0.f;
    float4 a0 = make_float4(0, 0, 0, 0), a1 = a0, a2 = a0, a3 = a0, a4 = a0;
    int i = off0;
    while (i < off1) {
        const bool two = (i + 1 < off1);
        const int e0 = perm[i];
        const int e1 = two ? perm[i + 1] : e0;
        const int t0 = e0 / EPT, t1 = e1 / EPT;       // wave-uniform
        const int s0 = esrc[e0], s1 = esrc[e1];
        const size_t rb0 = (size_t)s0 * NCAT, rb1 = (size_t)s1 * NCAT;
        const ushort4 ku0 = *(const ushort4*)(Ccat + rb0 + ((t0 * 4 + h) << 6) + f0);
        const ushort4 vu0 = *(const ushort4*)(Ccat + rb0 + voff);
        const ushort4 ku1 = *(const ushort4*)(Ccat + rb1 + ((t1 * 4 + h) << 6) + f0);
        const ushort4 vu1 = *(const ushort4*)(Ccat + rb1 + voff);
        float p0 = qx * bf2f(ku0.x) + qy * bf2f(ku0.y) + qz * bf2f(ku0.z) + qw * bf2f(ku0.w);
        float p1 = qx * bf2f(ku1.x) + qy * bf2f(ku1.y) + qz * bf2f(ku1.z) + qw * bf2f(ku1.w);
        p0 += __shfl_xor(p0, 1); p1 += __shfl_xor(p1, 1);
        p0 += __shfl_xor(p0, 2); p1 += __shfl_xor(p1, 2);
        p0 += __shfl_xor(p0, 4); p1 += __shfl_xor(p1, 4);
        p0 += __shfl_xor(p0, 8); p1 += __shfl_xor(p1, 8);
        {
            const float ex = __expf(p0);
            es += ex;
            const float mx = ex * bf2f(vu0.x), my = ex * bf2f(vu0.y);
            const float mz = ex * bf2f(vu0.z), mw = ex * bf2f(vu0.w);
            if (t0 == 0)      { a0.x += mx; a0.y += my; a0.z += mz; a0.w += mw; }
            else if (t0 == 1) { a1.x += mx; a1.y += my; a1.z += mz; a1.w += mw; }
            else if (t0 == 2) { a2.x += mx; a2.y += my; a2.z += mz; a2.w += mw; }
            else if (t0 == 3) { a3.x += mx; a3.y += my; a3.z += mz; a3.w += mw; }
            else              { a4.x += mx; a4.y += my; a4.z += mz; a4.w += mw; }
        }
        if (two) {
            const float ex = __expf(p1);
            es += ex;
            const float mx = ex * bf2f(vu1.x), my = ex * bf2f(vu1.y);
            const float mz = ex * bf2f(vu1.z), mw = ex * bf2f(vu1.w);
            if (t1 == 0)      { a0.x += mx; a0.y += my; a0.z += mz; a0.w += mw; }
            else if (t1 == 1) { a1.x += mx; a1.y += my; a1.z += mz; a1.w += mw; }
            else if (t1 == 2) { a2.x += mx; a2.y += my; a2.z += mz; a2.w += mw; }
            else if (t1 == 3) { a3.x += mx; a3.y += my; a3.z += mz; a3.w += mw; }
            else              { a4.x += mx; a4.y += my; a4.z += mz; a4.w += mw; }
        }
        i += two ? 2 : 1;
    }
    const float inv = 1.f / (es + 1e-16f);
    const size_t rr = (size_t)tgt * NHEAD + h;
    unsigned short* base = Acat + rr * (NTYPES * HDIM) + f0;
    ushort4 u;
    u.x = f2bf(a0.x * inv); u.y = f2bf(a0.y * inv); u.z = f2bf(a0.z * inv); u.w = f2bf(a0.w * inv);
    *(ushort4*)(base + 0 * HDIM) = u;
    u.x = f2bf(a1.x * inv); u.y = f2bf(a1.y * inv); u.z = f2bf(a1.z * inv); u.w = f2bf(a1.w * inv);
    *(ushort4*)(base + 1 * HDIM) = u;
    u.x = f2bf(a2.x * inv); u.y = f2bf(a2.y * inv); u.z = f2bf(a2.z * inv); u.w = f2bf(a2.w * inv);
    *(ushort4*)(base + 2 * HDIM) = u;
    u.x = f2bf(a3.x * inv); u.y = f2bf(a3.y * inv); u.z = f2bf(a3.z * inv); u.w = f2bf(a3.w * inv);
    *(ushort4*)(base + 3 * HDIM) = u;
    u.x = f2bf(a4.x * inv); u.y = f2bf(a4.y * inv); u.z = f2bf(a4.z * inv); u.w = f2bf(a4.w * inv);
    *(ushort4*)(base + 4 * HDIM) = u;
}

// ---- MFMA epilogue GEMM: aggVb[120000,64](bf16) = gelu(Acat[120000,320] @ vrelT^T) ----
__global__ __launch_bounds__(256) void gemm_cat_mfma(const unsigned short* __restrict__ Acat,
                                                     const unsigned short* __restrict__ vrelT,
                                                     unsigned short* __restrict__ aggVb) {
    __shared__ unsigned short As[256 * 40];
    __shared__ unsigned short Bs[64 * 40];
    const int brow0 = blockIdx.x * 256;
    const int t = threadIdx.x;
    const int wid = t >> 6, lane = t & 63;
    const int lrow = lane & 15, kb = lane >> 4;
    const int r0 = t >> 2, q0 = (t & 3) * 8;

    f32x4 acc[4][4];
#pragma unroll
    for (int m = 0; m < 4; ++m)
#pragma unroll
        for (int n = 0; n < 4; ++n) acc[m][n] = (f32x4)0.f;

    for (int kt = 0; kt < 320; kt += 32) {
        uint4 a[4];
#pragma unroll
        for (int i = 0; i < 4; ++i) {
            const int row = min(brow0 + r0 + 64 * i, 120000 - 1);
            a[i] = *(const uint4*)(Acat + (size_t)row * 320 + kt + q0);
        }
        const uint4 b0 = *(const uint4*)(vrelT + (size_t)r0 * 320 + kt + q0);
        __syncthreads();
#pragma unroll
        for (int i = 0; i < 4; ++i)
            *(uint4*)&As[(r0 + 64 * i) * 40 + q0] = a[i];
        *(uint4*)&Bs[r0 * 40 + q0] = b0;
        __syncthreads();
        short8 af[4], bf_[4];
#pragma unroll
        for (int m = 0; m < 4; ++m)
            af[m] = *(const short8*)&As[(wid * 64 + m * 16 + lrow) * 40 + kb * 8];
#pragma unroll
        for (int n = 0; n < 4; ++n)
            bf_[n] = *(const short8*)&Bs[(n * 16 + lrow) * 40 + kb * 8];
#pragma unroll
        for (int m = 0; m < 4; ++m)
#pragma unroll
            for (int n = 0; n < 4; ++n)
                acc[m][n] = __builtin_amdgcn_mfma_f32_16x16x32_bf16(af[m], bf_[n], acc[m][n], 0, 0, 0);
    }

#pragma unroll
    for (int m = 0; m < 4; ++m) {
        const int gr0 = brow0 + wid * 64 + m * 16 + kb * 4;
#pragma unroll
        for (int v = 0; v < 4; ++v) {
            const int grow = gr0 + v;
            if (grow < 120000) {
#pragma unroll
                for (int n = 0; n < 4; ++n) {
                    const int gcol = n * 16 + lrow;
                    const float x = acc[m][n][v];
                    const float g = 0.5f * x * (1.f + erff(x * 0.7071067811865475f));
                    aggVb[(size_t)grow * 64 + gcol] = f2bf(g);
                }
            }
        }
    }
}

// ---- MFMA out GEMM: out[30000,256] = sa*(aggVb @ Wob^T + out_b) + sb*h ----
__global__ __launch_bounds__(256) void gemm_out_mfma(const unsigned short* __restrict__ A,
                                                     const unsigned short* __restrict__ Wob,
                                                     const float* __restrict__ bias,
                                                     float* __restrict__ C,
                                                     const float* __restrict__ hres,
                                                     const float* __restrict__ skip) {
    __shared__ unsigned short As[128 * 40];
    __shared__ unsigned short Bs[128 * 40];
    const int brow0 = blockIdx.x * 128;
    const int bcol0 = blockIdx.y * 128;
    const int t = threadIdx.x;
    const int wid = t >> 6, lane = t & 63;
    const int wr = wid >> 1, wc = wid & 1;
    const int lrow = lane & 15, kb = lane >> 4;
    const int r0 = t >> 2, q0 = t & 3;
    const int r1 = (t + 256) >> 2, q1 = t & 3;

    f32x4 acc[4][4];
#pragma unroll
    for (int m = 0; m < 4; ++m)
#pragma unroll
        for (int n = 0; n < 4; ++n) acc[m][n] = (f32x4)0.f;

    for (int kt = 0; kt < 256; kt += 32) {
        const int ar0 = min(brow0 + r0, N_NODES - 1);
        const int ar1 = min(brow0 + r1, N_NODES - 1);
        const uint4 a0 = *(const uint4*)(A + (size_t)ar0 * 256 + kt + q0 * 8);
        const uint4 a1 = *(const uint4*)(A + (size_t)ar1 * 256 + kt + q1 * 8);
        const uint4 b0 = *(const uint4*)(Wob + (size_t)(bcol0 + r0) * 256 + kt + q0 * 8);
        const uint4 b1 = *(const uint4*)(Wob + (size_t)(bcol0 + r1) * 256 + kt + q1 * 8);
        __syncthreads();
        *(uint4*)&As[r0 * 40 + q0 * 8] = a0;
        *(uint4*)&As[r1 * 40 + q1 * 8] = a1;
        *(uint4*)&Bs[r0 * 40 + q0 * 8] = b0;
        *(uint4*)&Bs[r1 * 40 + q1 * 8] = b1;
        __syncthreads();
        short8 af[4], bf_[4];
#pragma unroll
        for (int m = 0; m < 4; ++m)
            af[m] = *(const short8*)&As[(wr * 64 + m * 16 + lrow) * 40 + kb * 8];
#pragma unroll
        for (int n = 0; n < 4; ++n)
            bf_[n] = *(const short8*)&Bs[(wc * 64 + n * 16 + lrow) * 40 + kb * 8];
#pragma unroll
        for (int m = 0; m < 4; ++m)
#pragma unroll
            for (int n = 0; n < 4; ++n)
                acc[m][n] = __builtin_amdgcn_mfma_f32_16x16x32_bf16(af[m], bf_[n], acc[m][n], 0, 0, 0);
    }

    const float s = skip[0];
    const float sa = 1.f / (1.f + expf(-s));
    const float sb = 1.f - sa;
    float bias4[4];
#pragma unroll
    for (int n = 0; n < 4; ++n) bias4[n] = bias[bcol0 + wc * 64 + n * 16 + lrow];
#pragma unroll
    for (int m = 0; m < 4; ++m) {
        const int gr0 = brow0 + wr * 64 + m * 16 + kb * 4;
#pragma unroll
        for (int v = 0; v < 4; ++v) {
            const int grow = gr0 + v;
            if (grow < N_NODES) {
#pragma unroll
                for (int n = 0; n < 4; ++n) {
                    const int gcol = bcol0 + wc * 64 + n * 16 + lrow;
                    const float val = acc[m][n][v] + bias4[n];
                    C[(size_t)grow * 256 + gcol] = sa * val + sb * hres[(size_t)grow * 256 + gcol];
                }
            }
        }
    }
}

extern "C" void kernel_launch(void* const* d_in, const int* in_sizes, int n_in,
                              void* d_out, int out_size, void* d_ws, size_t ws_size,
                              hipStream_t stream) {
    const float* h      = (const float*)d_in[0];
    const int*   esrc   = (const int*)d_in[1];
    const int*   etgt   = (const int*)d_in[2];
    const float* kqv_w  = (const float*)d_in[3];
    const float* kqv_b  = (const float*)d_in[4];
    const float* out_w  = (const float*)d_in[5];
    const float* out_b  = (const float*)d_in[6];
    const float* k_rel  = (const float*)d_in[7];
    const float* v_rel  = (const float*)d_in[8];
    const float* skip   = (const float*)d_in[9];
    const float* p_rel  = (const float*)d_in[10];
    float* out = (float*)d_out;

    // workspace layout (float-sized slots):
    float* ws = (float*)d_ws;
    unsigned short* Ccat     = (unsigned short*)ws;                 // 26,880,000 slots [0 .. 26.88M)
    int*            deg      = (int*)(ws + 26880000);               //     30,000 -> 26,910,000
    int*            off      = (int*)(ws + 26910000);               //     30,000 -> 26,940,000
    int*            cursor   = (int*)(ws + 26940000);               //     30,000 -> 26,970,000
    int*            perm     = (int*)(ws + 26970000);               //    200,000 -> 27,170,000
    unsigned short* aggVb    = (unsigned short*)(ws + 27170000);    // 3,840,000 slots -> 31,010,000
    unsigned short* Acat     = (unsigned short*)(ws + 31010000);    // 19,200,000 slots -> 50,210,000
    // LATE-READ buffers (consumed AFTER Acat is written) -> past Acat's end:
    unsigned short* vrelT    = (unsigned short*)(ws + 50210000);    // 10,240 slots -> 50,220,240
    unsigned short* Wob      = (unsigned short*)(ws + 50220240);    // 32,768 slots -> 50,253,008
    // EARLY-DEAD aliases inside Acat's span (read only BEFORE edge_fused writes Acat):
    unsigned short* hb       = (unsigned short*)(ws + 41530000);    // 3,840,000 slots -> ends 45,370,000
    unsigned short* Wcat     = (unsigned short*)(ws + 45370000);    // 229,376 slots -> ends 45,599,376
    float*          bias_cat = ws + 45600000;                       // 1,792 -> ends 45,601,792 (< 50.21M ok)
    // total footprint: 50,253,008 float slots = 201.0 MB

    hipLaunchKernelGGL(init_kernel, dim3(118), dim3(256), 0, stream, deg);
    hipLaunchKernelGGL(hist_kernel, dim3(782), dim3(256), 0, stream, etgt, deg);
    hipLaunchKernelGGL(scan_kernel, dim3(1), dim3(1024), 0, stream, deg, off, cursor);
    hipLaunchKernelGGL(scatter_kernel, dim3(782), dim3(256), 0, stream, etgt, cursor, perm);
    hipLaunchKernelGGL(prep_all, dim3(9628), dim3(256), 0, stream,
                       kqv_w, kqv_b, k_rel, p_rel, h, v_rel, out_w,
                       Wcat, bias_cat, hb, vrelT, Wob);
    hipLaunchKernelGGL(mfma_gemm, dim3(3290), dim3(256), 0, stream,
                       hb, Wcat, bias_cat, Ccat);
    hipLaunchKernelGGL(edge_fused, dim3(N_NODES / 4), dim3(256), 0, stream,
                       Ccat, esrc, off, perm, Acat);
    hipLaunchKernelGGL(gemm_cat_mfma, dim3(469), dim3(256), 0, stream,
                       Acat, vrelT, aggVb);
    hipLaunchKernelGGL(gemm_out_mfma, dim3(235, 2), dim3(256), 0, stream,
                       aggVb, Wob, out_b, out, h, skip);
}

// Round 10
// 233.048 us; speedup vs baseline: 4.7890x; 1.0166x over previous
//
#include <hip/hip_runtime.h>
#include <hip/hip_bf16.h>
#include <math.h>

#define N_NODES 30000
#define NHEAD   4
#define HDIM    64
#define NTYPES  5
#define EPT     40000
#define TE      (NTYPES * EPT)
#define KDIM    256
#define NCAT    1792   // 1280 Ktil | 256 Q | 256 V

typedef __attribute__((ext_vector_type(8))) short short8;
typedef __attribute__((ext_vector_type(4))) float f32x4;

__device__ __forceinline__ unsigned short f2bf(float f) {
    __hip_bfloat16 h = __float2bfloat16(f);
    return *reinterpret_cast<unsigned short*>(&h);
}
__device__ __forceinline__ float bf2f(unsigned short u) {
    return __uint_as_float((unsigned)u << 16);
}

// async global->LDS, 16B per lane. LDS dest is wave-uniform base + lane*16 (linear).
__device__ __forceinline__ void gload16(const unsigned short* g, unsigned short* l) {
    __builtin_amdgcn_global_load_lds((const __attribute__((address_space(1))) void*)g,
                                     (__attribute__((address_space(3))) void*)l, 16, 0, 0);
}

// ---- init: zero deg ----
__global__ __launch_bounds__(256) void init_kernel(int* __restrict__ deg) {
    const int gid = blockIdx.x * blockDim.x + threadIdx.x;
    if (gid < N_NODES) deg[gid] = 0;
}

// ---- CSR build: histogram ----
__global__ __launch_bounds__(256) void hist_kernel(const int* __restrict__ etgt,
                                                   int* __restrict__ deg) {
    const int stride = gridDim.x * blockDim.x;
    for (int i = blockIdx.x * blockDim.x + threadIdx.x; i < TE; i += stride)
        atomicAdd(&deg[etgt[i]], 1);
}

// ---- CSR build: single-block exclusive scan over 30000 degrees ----
__global__ __launch_bounds__(1024) void scan_kernel(const int* __restrict__ deg,
                                                    int* __restrict__ off,
                                                    int* __restrict__ cursor) {
    __shared__ int sums[1024];
    const int t = threadIdx.x;
    int local[30];
    int s = 0;
    const int base = t * 30;
#pragma unroll
    for (int j = 0; j < 30; ++j) {
        const int idx = base + j;
        const int d = (idx < N_NODES) ? deg[idx] : 0;
        local[j] = d;
        s += d;
    }
    sums[t] = s;
    __syncthreads();
    for (int d = 1; d < 1024; d <<= 1) {
        const int v = (t >= d) ? sums[t - d] : 0;
        __syncthreads();
        sums[t] += v;
        __syncthreads();
    }
    int run = (t > 0) ? sums[t - 1] : 0;
#pragma unroll
    for (int j = 0; j < 30; ++j) {
        const int idx = base + j;
        if (idx < N_NODES) {
            off[idx] = run;
            cursor[idx] = run;
            run += local[j];
        }
    }
}

// ---- CSR build: scatter PACKED (src | t<<16) into per-target buckets ----
// Kills the esrc[] dependent-load level in edge_fused (src<2^15, t<8).
__global__ __launch_bounds__(256) void scatter_kernel(const int* __restrict__ etgt,
                                                      const int* __restrict__ esrc,
                                                      int* __restrict__ cursor,
                                                      int* __restrict__ perm) {
    const int stride = gridDim.x * blockDim.x;
    for (int e = blockIdx.x * blockDim.x + threadIdx.x; e < TE; e += stride) {
        const int pos = atomicAdd(&cursor[etgt[e]], 1);
        perm[pos] = esrc[e] | ((e / EPT) << 16);
    }
}

// ---- merged prep: [0,1792) weight_prep | [1792,9292) h2bf | [9292,9372) vrelT | [9372,9628) owb ----
__global__ __launch_bounds__(256) void prep_all(const float* __restrict__ kqv_w,
                                                const float* __restrict__ kqv_b,
                                                const float* __restrict__ k_rel,
                                                const float* __restrict__ p_rel,
                                                const float* __restrict__ h,
                                                const float* __restrict__ v_rel,
                                                const float* __restrict__ out_w,
                                                unsigned short* __restrict__ Wcat,
                                                float* __restrict__ bias_cat,
                                                unsigned short* __restrict__ hb,
                                                unsigned short* __restrict__ vrelT,
                                                unsigned short* __restrict__ Wob) {
    const int bid = blockIdx.x;
    const int tid = threadIdx.x;
    if (bid < 1792) {
        const int r = bid, f = tid;
        if (r < 1280) {
            const int t = r >> 8, hh = (r >> 6) & 3, d = r & 63;
            const float sc = 0.125f * p_rel[t * NHEAD + hh];
            float acc = 0.f;
#pragma unroll
            for (int fp = 0; fp < 64; ++fp)
                acc = fmaf(kqv_w[(size_t)(hh * 64 + fp) * 256 + f], k_rel[t * 4096 + fp * 64 + d], acc);
            Wcat[(size_t)r * 256 + f] = f2bf(acc * sc);
            if (f == 0) {
                float b = 0.f;
#pragma unroll
                for (int fp = 0; fp < 64; ++fp)
                    b = fmaf(kqv_b[hh * 64 + fp], k_rel[t * 4096 + fp * 64 + d], b);
                bias_cat[r] = b * sc;
            }
        } else {
            const int src_row = r - 1024;  // 1280->256 (Q), 1536->512 (V)
            Wcat[(size_t)r * 256 + f] = f2bf(kqv_w[(size_t)src_row * 256 + f]);
            if (f == 0) bias_cat[r] = kqv_b[src_row];
        }
    } else if (bid < 9292) {
        const int i = (bid - 1792) * 256 + tid;   // exactly 1,920,000 float4s
        const float4 v = ((const float4*)h)[i];
        ushort4 u;
        u.x = f2bf(v.x); u.y = f2bf(v.y); u.z = f2bf(v.z); u.w = f2bf(v.w);
        ((ushort4*)hb)[i] = u;
    } else if (bid < 9372) {
        const int idx = (bid - 9292) * 256 + tid;
        if (idx < 64 * 320) {
            const int f = idx / 320, k = idx - f * 320;
            vrelT[f * 320 + k] = f2bf(v_rel[(k >> 6) * 4096 + (k & 63) * 64 + f]);
        }
    } else {
        const int i = (bid - 9372) * 256 + tid;   // exactly 65,536
        Wob[i] = f2bf(out_w[i]);
    }
}

// ---- MFMA GEMM: Ccat[30000,1792](bf16) = hb[30000,256] @ Wcat^T + bias_cat ----
__global__ __launch_bounds__(256) void mfma_gemm(const unsigned short* __restrict__ hb,
                                                 const unsigned short* __restrict__ Wcat,
                                                 const float* __restrict__ bias_cat,
                                                 unsigned short* __restrict__ Ccat) {
    __shared__ unsigned short As[2][128 * 32];
    __shared__ unsigned short Bs[2][128 * 32];
    // bijective chunked swizzle over 3290 = 235*14 blocks, 8 XCDs (m204)
    const int orig = blockIdx.x;
    const int xcd = orig & 7, pos = orig >> 3;
    const int q = 3290 / 8, r = 3290 % 8;  // 411, 2
    const int wgid = (xcd < r ? xcd * (q + 1) : r * (q + 1) + (xcd - r) * q) + pos;
    const int brow0 = (wgid / 14) * 128;
    const int bcol0 = (wgid % 14) * 128;

    const int t = threadIdx.x;
    const int wid = t >> 6, lane = t & 63;
    const int wr = wid >> 1, wc = wid & 1;
    const int lrow = lane & 15, kb = lane >> 4;
    const int srow = lane >> 2;
    const int schunk = ((lane & 3) ^ ((lane >> 3) & 3)) * 8;   // staged (swizzled) chunk
    const int rchunk = (kb ^ ((lrow >> 1) & 3)) * 8;           // swizzled read chunk

    const int arow0 = min(brow0 + wid * 16 + srow, N_NODES - 1);
    const int arow1 = min(brow0 + 64 + wid * 16 + srow, N_NODES - 1);
    const int brw0 = bcol0 + wid * 16 + srow;        // always < 1792
    const int brw1 = bcol0 + 64 + wid * 16 + srow;

    auto stage = [&](int buf, int kt) {
        gload16(hb + (size_t)arow0 * KDIM + kt + schunk, &As[buf][wid * 512]);
        gload16(hb + (size_t)arow1 * KDIM + kt + schunk, &As[buf][2048 + wid * 512]);
        gload16(Wcat + (size_t)brw0 * KDIM + kt + schunk, &Bs[buf][wid * 512]);
        gload16(Wcat + (size_t)brw1 * KDIM + kt + schunk, &Bs[buf][2048 + wid * 512]);
    };

    f32x4 acc[4][4];
#pragma unroll
    for (int m = 0; m < 4; ++m)
#pragma unroll
        for (int n = 0; n < 4; ++n) acc[m][n] = (f32x4)0.f;

    stage(0, 0);
    __syncthreads();
    int cur = 0;
    for (int kt = 0; kt < KDIM; kt += 32) {
        if (kt + 32 < KDIM) stage(cur ^ 1, kt + 32);
        short8 af[4], bfr[4];
#pragma unroll
        for (int m = 0; m < 4; ++m)
            af[m] = *(const short8*)&As[cur][(wr * 64 + m * 16 + lrow) * 32 + rchunk];
#pragma unroll
        for (int n = 0; n < 4; ++n)
            bfr[n] = *(const short8*)&Bs[cur][(wc * 64 + n * 16 + lrow) * 32 + rchunk];
#pragma unroll
        for (int m = 0; m < 4; ++m)
#pragma unroll
            for (int n = 0; n < 4; ++n)
                acc[m][n] = __builtin_amdgcn_mfma_f32_16x16x32_bf16(af[m], bfr[n], acc[m][n], 0, 0, 0);
        __syncthreads();
        cur ^= 1;
    }

    // ---- LDS-transpose epilogue: dwordx4 C-stores ----
    unsigned short* Ts = &As[0][0];
    float bias4[4];
#pragma unroll
    for (int n = 0; n < 4; ++n) bias4[n] = bias_cat[bcol0 + wc * 64 + n * 16 + lrow];
    const int lrw = wr * 16 + kb * 4;
    const int lcw = wc * 64 + lrow;
#pragma unroll
    for (int m = 0; m < 4; ++m) {
        __syncthreads();
#pragma unroll
        for (int n = 0; n < 4; ++n)
#pragma unroll
            for (int v = 0; v < 4; ++v)
                Ts[(lrw + v) * 132 + lcw + n * 16] = f2bf(acc[m][n][v] + bias4[n]);
        __syncthreads();
#pragma unroll
        for (int rd = 0; rd < 2; ++rd) {
            const int lr = (t >> 4) + rd * 16;          // 0..31
            const int c0 = (t & 15) * 8;                // 0..120 step 8
            const int grow = brow0 + (lr >> 4) * 64 + m * 16 + (lr & 15);
            if (grow < N_NODES) {
                const uint2 lo = *(const uint2*)&Ts[lr * 132 + c0];
                const uint2 hi = *(const uint2*)&Ts[lr * 132 + c0 + 4];
                const uint4 o = make_uint4(lo.x, lo.y, hi.x, hi.y);
                *(uint4*)&Ccat[(size_t)grow * NCAT + bcol0 + c0] = o;
            }
        }
    }
}

// ---- fused edge pass: one wave per target, packed-src CSR walk.
// ARITHMETIC STRUCTURE = round 8 exactly (unroll-2, sequential es adds) — only the
// src/type derivation changed (unpack from perm instead of loading esrc[e]).
__global__ __launch_bounds__(256) void edge_fused(const unsigned short* __restrict__ Ccat,
                                                  const int* __restrict__ off,
                                                  const int* __restrict__ perm,
                                                  unsigned short* __restrict__ Acat) {
    const int wid = threadIdx.x >> 6, lane = threadIdx.x & 63;
    const int tgt = (blockIdx.x << 2) + wid;
    const int h = lane >> 4, f0 = (lane & 15) << 2;
    const int off0 = off[tgt];
    const int off1 = (tgt == N_NODES - 1) ? TE : off[tgt + 1];
    const ushort4 qu = *(const ushort4*)(Ccat + (size_t)tgt * NCAT + 1280 + (h << 6) + f0);
    const float qx = bf2f(qu.x), qy = bf2f(qu.y), qz = bf2f(qu.z), qw = bf2f(qu.w);
    const int voff = 1536 + (h << 6) + f0;
    float es = 0.f;
    float4 a0 = make_float4(0, 0, 0, 0), a1 = a0, a2 = a0, a3 = a0, a4 = a0;
    int i = off0;
    while (i < off1) {
        const bool two = (i + 1 < off1);
        const int pk0 = perm[i];
        const int pk1 = two ? perm[i + 1] : pk0;
        const int s0 = pk0 & 0xFFFF, t0 = pk0 >> 16;
        const int s1 = pk1 & 0xFFFF, t1 = pk1 >> 16;
        const size_t rb0 = (size_t)s0 * NCAT, rb1 = (size_t)s1 * NCAT;
        // issue all 4 gathers before any compute (2x memory-level parallelism)
        const ushort4 ku0 = *(const ushort4*)(Ccat + rb0 + ((t0 * 4 + h) << 6) + f0);
        const ushort4 vu0 = *(const ushort4*)(Ccat + rb0 + voff);
        const ushort4 ku1 = *(const ushort4*)(Ccat + rb1 + ((t1 * 4 + h) << 6) + f0);
        const ushort4 vu1 = *(const ushort4*)(Ccat + rb1 + voff);
        float p0 = qx * bf2f(ku0.x) + qy * bf2f(ku0.y) + qz * bf2f(ku0.z) + qw * bf2f(ku0.w);
        float p1 = qx * bf2f(ku1.x) + qy * bf2f(ku1.y) + qz * bf2f(ku1.z) + qw * bf2f(ku1.w);
        p0 += __shfl_xor(p0, 1); p1 += __shfl_xor(p1, 1);
        p0 += __shfl_xor(p0, 2); p1 += __shfl_xor(p1, 2);
        p0 += __shfl_xor(p0, 4); p1 += __shfl_xor(p1, 4);
        p0 += __shfl_xor(p0, 8); p1 += __shfl_xor(p1, 8);
        {
            const float ex = __expf(p0);
            es += ex;
            const float mx = ex * bf2f(vu0.x), my = ex * bf2f(vu0.y);
            const float mz = ex * bf2f(vu0.z), mw = ex * bf2f(vu0.w);
            if (t0 == 0)      { a0.x += mx; a0.y += my; a0.z += mz; a0.w += mw; }
            else if (t0 == 1) { a1.x += mx; a1.y += my; a1.z += mz; a1.w += mw; }
            else if (t0 == 2) { a2.x += mx; a2.y += my; a2.z += mz; a2.w += mw; }
            else if (t0 == 3) { a3.x += mx; a3.y += my; a3.z += mz; a3.w += mw; }
            else              { a4.x += mx; a4.y += my; a4.z += mz; a4.w += mw; }
        }
        if (two) {
            const float ex = __expf(p1);
            es += ex;
            const float mx = ex * bf2f(vu1.x), my = ex * bf2f(vu1.y);
            const float mz = ex * bf2f(vu1.z), mw = ex * bf2f(vu1.w);
            if (t1 == 0)      { a0.x += mx; a0.y += my; a0.z += mz; a0.w += mw; }
            else if (t1 == 1) { a1.x += mx; a1.y += my; a1.z += mz; a1.w += mw; }
            else if (t1 == 2) { a2.x += mx; a2.y += my; a2.z += mz; a2.w += mw; }
            else if (t1 == 3) { a3.x += mx; a3.y += my; a3.z += mz; a3.w += mw; }
            else              { a4.x += mx; a4.y += my; a4.z += mz; a4.w += mw; }
        }
        i += two ? 2 : 1;
    }
    const float inv = 1.f / (es + 1e-16f);
    const size_t rr = (size_t)tgt * NHEAD + h;
    unsigned short* base = Acat + rr * (NTYPES * HDIM) + f0;
    ushort4 u;
    u.x = f2bf(a0.x * inv); u.y = f2bf(a0.y * inv); u.z = f2bf(a0.z * inv); u.w = f2bf(a0.w * inv);
    *(ushort4*)(base + 0 * HDIM) = u;
    u.x = f2bf(a1.x * inv); u.y = f2bf(a1.y * inv); u.z = f2bf(a1.z * inv); u.w = f2bf(a1.w * inv);
    *(ushort4*)(base + 1 * HDIM) = u;
    u.x = f2bf(a2.x * inv); u.y = f2bf(a2.y * inv); u.z = f2bf(a2.z * inv); u.w = f2bf(a2.w * inv);
    *(ushort4*)(base + 2 * HDIM) = u;
    u.x = f2bf(a3.x * inv); u.y = f2bf(a3.y * inv); u.z = f2bf(a3.z * inv); u.w = f2bf(a3.w * inv);
    *(ushort4*)(base + 3 * HDIM) = u;
    u.x = f2bf(a4.x * inv); u.y = f2bf(a4.y * inv); u.z = f2bf(a4.z * inv); u.w = f2bf(a4.w * inv);
    *(ushort4*)(base + 4 * HDIM) = u;
}

// ---- MFMA epilogue GEMM: aggVb[120000,64](bf16) = gelu(Acat[120000,320] @ vrelT^T) ----
__global__ __launch_bounds__(256) void gemm_cat_mfma(const unsigned short* __restrict__ Acat,
                                                     const unsigned short* __restrict__ vrelT,
                                                     unsigned short* __restrict__ aggVb) {
    __shared__ unsigned short As[256 * 40];
    __shared__ unsigned short Bs[64 * 40];
    const int brow0 = blockIdx.x * 256;
    const int t = threadIdx.x;
    const int wid = t >> 6, lane = t & 63;
    const int lrow = lane & 15, kb = lane >> 4;
    const int r0 = t >> 2, q0 = (t & 3) * 8;

    f32x4 acc[4][4];
#pragma unroll
    for (int m = 0; m < 4; ++m)
#pragma unroll
        for (int n = 0; n < 4; ++n) acc[m][n] = (f32x4)0.f;

    for (int kt = 0; kt < 320; kt += 32) {
        uint4 a[4];
#pragma unroll
        for (int i = 0; i < 4; ++i) {
            const int row = min(brow0 + r0 + 64 * i, 120000 - 1);
            a[i] = *(const uint4*)(Acat + (size_t)row * 320 + kt + q0);
        }
        const uint4 b0 = *(const uint4*)(vrelT + (size_t)r0 * 320 + kt + q0);
        __syncthreads();
#pragma unroll
        for (int i = 0; i < 4; ++i)
            *(uint4*)&As[(r0 + 64 * i) * 40 + q0] = a[i];
        *(uint4*)&Bs[r0 * 40 + q0] = b0;
        __syncthreads();
        short8 af[4], bf_[4];
#pragma unroll
        for (int m = 0; m < 4; ++m)
            af[m] = *(const short8*)&As[(wid * 64 + m * 16 + lrow) * 40 + kb * 8];
#pragma unroll
        for (int n = 0; n < 4; ++n)
            bf_[n] = *(const short8*)&Bs[(n * 16 + lrow) * 40 + kb * 8];
#pragma unroll
        for (int m = 0; m < 4; ++m)
#pragma unroll
            for (int n = 0; n < 4; ++n)
                acc[m][n] = __builtin_amdgcn_mfma_f32_16x16x32_bf16(af[m], bf_[n], acc[m][n], 0, 0, 0);
    }

#pragma unroll
    for (int m = 0; m < 4; ++m) {
        const int gr0 = brow0 + wid * 64 + m * 16 + kb * 4;
#pragma unroll
        for (int v = 0; v < 4; ++v) {
            const int grow = gr0 + v;
            if (grow < 120000) {
#pragma unroll
                for (int n = 0; n < 4; ++n) {
                    const int gcol = n * 16 + lrow;
                    const float x = acc[m][n][v];
                    const float g = 0.5f * x * (1.f + erff(x * 0.7071067811865475f));
                    aggVb[(size_t)grow * 64 + gcol] = f2bf(g);
                }
            }
        }
    }
}

// ---- MFMA out GEMM: out[30000,256] = sa*(aggVb @ Wob^T + out_b) + sb*h ----
__global__ __launch_bounds__(256) void gemm_out_mfma(const unsigned short* __restrict__ A,
                                                     const unsigned short* __restrict__ Wob,
                                                     const float* __restrict__ bias,
                                                     float* __restrict__ C,
                                                     const float* __restrict__ hres,
                                                     const float* __restrict__ skip) {
    __shared__ unsigned short As[128 * 40];
    __shared__ unsigned short Bs[128 * 40];
    const int brow0 = blockIdx.x * 128;
    const int bcol0 = blockIdx.y * 128;
    const int t = threadIdx.x;
    const int wid = t >> 6, lane = t & 63;
    const int wr = wid >> 1, wc = wid & 1;
    const int lrow = lane & 15, kb = lane >> 4;
    const int r0 = t >> 2, q0 = t & 3;
    const int r1 = (t + 256) >> 2, q1 = t & 3;

    f32x4 acc[4][4];
#pragma unroll
    for (int m = 0; m < 4; ++m)
#pragma unroll
        for (int n = 0; n < 4; ++n) acc[m][n] = (f32x4)0.f;

    for (int kt = 0; kt < 256; kt += 32) {
        const int ar0 = min(brow0 + r0, N_NODES - 1);
        const int ar1 = min(brow0 + r1, N_NODES - 1);
        const uint4 a0 = *(const uint4*)(A + (size_t)ar0 * 256 + kt + q0 * 8);
        const uint4 a1 = *(const uint4*)(A + (size_t)ar1 * 256 + kt + q1 * 8);
        const uint4 b0 = *(const uint4*)(Wob + (size_t)(bcol0 + r0) * 256 + kt + q0 * 8);
        const uint4 b1 = *(const uint4*)(Wob + (size_t)(bcol0 + r1) * 256 + kt + q1 * 8);
        __syncthreads();
        *(uint4*)&As[r0 * 40 + q0 * 8] = a0;
        *(uint4*)&As[r1 * 40 + q1 * 8] = a1;
        *(uint4*)&Bs[r0 * 40 + q0 * 8] = b0;
        *(uint4*)&Bs[r1 * 40 + q1 * 8] = b1;
        __syncthreads();
        short8 af[4], bf_[4];
#pragma unroll
        for (int m = 0; m < 4; ++m)
            af[m] = *(const short8*)&As[(wr * 64 + m * 16 + lrow) * 40 + kb * 8];
#pragma unroll
        for (int n = 0; n < 4; ++n)
            bf_[n] = *(const short8*)&Bs[(wc * 64 + n * 16 + lrow) * 40 + kb * 8];
#pragma unroll
        for (int m = 0; m < 4; ++m)
#pragma unroll
            for (int n = 0; n < 4; ++n)
                acc[m][n] = __builtin_amdgcn_mfma_f32_16x16x32_bf16(af[m], bf_[n], acc[m][n], 0, 0, 0);
    }

    const float s = skip[0];
    const float sa = 1.f / (1.f + expf(-s));
    const float sb = 1.f - sa;
    float bias4[4];
#pragma unroll
    for (int n = 0; n < 4; ++n) bias4[n] = bias[bcol0 + wc * 64 + n * 16 + lrow];
#pragma unroll
    for (int m = 0; m < 4; ++m) {
        const int gr0 = brow0 + wr * 64 + m * 16 + kb * 4;
#pragma unroll
        for (int v = 0; v < 4; ++v) {
            const int grow = gr0 + v;
            if (grow < N_NODES) {
#pragma unroll
                for (int n = 0; n < 4; ++n) {
                    const int gcol = bcol0 + wc * 64 + n * 16 + lrow;
                    const float val = acc[m][n][v] + bias4[n];
                    C[(size_t)grow * 256 + gcol] = sa * val + sb * hres[(size_t)grow * 256 + gcol];
                }
            }
        }
    }
}

extern "C" void kernel_launch(void* const* d_in, const int* in_sizes, int n_in,
                              void* d_out, int out_size, void* d_ws, size_t ws_size,
                              hipStream_t stream) {
    const float* h      = (const float*)d_in[0];
    const int*   esrc   = (const int*)d_in[1];
    const int*   etgt   = (const int*)d_in[2];
    const float* kqv_w  = (const float*)d_in[3];
    const float* kqv_b  = (const float*)d_in[4];
    const float* out_w  = (const float*)d_in[5];
    const float* out_b  = (const float*)d_in[6];
    const float* k_rel  = (const float*)d_in[7];
    const float* v_rel  = (const float*)d_in[8];
    const float* skip   = (const float*)d_in[9];
    const float* p_rel  = (const float*)d_in[10];
    float* out = (float*)d_out;

    // workspace layout (float-sized slots):
    float* ws = (float*)d_ws;
    unsigned short* Ccat     = (unsigned short*)ws;                 // 26,880,000 slots [0 .. 26.88M)
    int*            deg      = (int*)(ws + 26880000);               //     30,000 -> 26,910,000
    int*            off      = (int*)(ws + 26910000);               //     30,000 -> 26,940,000
    int*            cursor   = (int*)(ws + 26940000);               //     30,000 -> 26,970,000
    int*            perm     = (int*)(ws + 26970000);               //    200,000 -> 27,170,000
    unsigned short* aggVb    = (unsigned short*)(ws + 27170000);    // 3,840,000 slots -> 31,010,000
    unsigned short* Acat     = (unsigned short*)(ws + 31010000);    // 19,200,000 slots -> 50,210,000
    // LATE-READ buffers (consumed AFTER Acat is written) -> past Acat's end:
    unsigned short* vrelT    = (unsigned short*)(ws + 50210000);    // 10,240 slots -> 50,220,240
    unsigned short* Wob      = (unsigned short*)(ws + 50220240);    // 32,768 slots -> 50,253,008
    // EARLY-DEAD aliases inside Acat's span (read only BEFORE edge_fused writes Acat):
    unsigned short* hb       = (unsigned short*)(ws + 41530000);    // 3,840,000 slots -> ends 45,370,000
    unsigned short* Wcat     = (unsigned short*)(ws + 45370000);    // 229,376 slots -> ends 45,599,376
    float*          bias_cat = ws + 45600000;                       // 1,792 -> ends 45,601,792 (< 50.21M ok)
    // total footprint: 50,253,008 float slots = 201.0 MB

    hipLaunchKernelGGL(init_kernel, dim3(118), dim3(256), 0, stream, deg);
    hipLaunchKernelGGL(hist_kernel, dim3(782), dim3(256), 0, stream, etgt, deg);
    hipLaunchKernelGGL(scan_kernel, dim3(1), dim3(1024), 0, stream, deg, off, cursor);
    hipLaunchKernelGGL(scatter_kernel, dim3(782), dim3(256), 0, stream, etgt, esrc, cursor, perm);
    hipLaunchKernelGGL(prep_all, dim3(9628), dim3(256), 0, stream,
                       kqv_w, kqv_b, k_rel, p_rel, h, v_rel, out_w,
                       Wcat, bias_cat, hb, vrelT, Wob);
    hipLaunchKernelGGL(mfma_gemm, dim3(3290), dim3(256), 0, stream,
                       hb, Wcat, bias_cat, Ccat);
    hipLaunchKernelGGL(edge_fused, dim3(N_NODES / 4), dim3(256), 0, stream,
                       Ccat, off, perm, Acat);
    hipLaunchKernelGGL(gemm_cat_mfma, dim3(469), dim3(256), 0, stream,
                       Acat, vrelT, aggVb);
    hipLaunchKernelGGL(gemm_out_mfma, dim3(235, 2), dim3(256), 0, stream,
                       aggVb, Wob, out_b, out, h, skip);
}